// Round 7
// baseline (510.947 us; speedup 1.0000x reference)
//
#include <hip/hip_runtime.h>
#include <hip/hip_bf16.h>

#define B_ROWS 65536
#define D_IN   128
#define H_DIM  512
#define E_DIM  64
#define K_CODES 4096

typedef __bf16 bf16;
typedef __attribute__((ext_vector_type(8))) __bf16 bf16x8;
typedef __attribute__((ext_vector_type(4))) float f32x4;

// async global->LDS, 16 B per lane; LDS dest = wave-uniform base + lane*16
__device__ __forceinline__ void gld_lds16(const bf16* g, bf16* l)
{
    __builtin_amdgcn_global_load_lds((const __attribute__((address_space(1))) void*)g,
                                     (__attribute__((address_space(3))) void*)l,
                                     16, 0, 0);
}

// ---------------------------------------------------------------------------
// bf16 MFMA GEMM, BM=128, BK=32, single-barrier double-buffered K-loop.
// C[M,N] = act(A[M,K] @ W[K,N] (*scale) + shift).  WT = W^T [N][K].
// XCD-aware 1-D grid swizzle (same-panel col-blocks adjacent + XCD-pinned).
// LDS rows 32-wide unpadded, XOR k-group swizzle (2-way-only read phases).
// CONV_A: A is fp32, converted to bf16 during staging (VGPR path).
// FUSE_ZN (BN=64): also emit zn = 0.5 * z/||z||.
// ---------------------------------------------------------------------------
template<int BN, int NCB, bool CONV_A, bool OUT_F32, bool USE_SCALE, bool RELU, bool FUSE_ZN>
__global__ __launch_bounds__(256)
void mfma_gemm(const void* __restrict__ Ap, const bf16* __restrict__ WT,
               const float* __restrict__ scale, const float* __restrict__ shift,
               void* __restrict__ Cout, bf16* __restrict__ Zn,
               int M, int N, int K)
{
    constexpr int NT = BN / 32;
    __shared__ bf16 As[2][128 * 32];
    __shared__ bf16 Bs[2][BN * 32];
    __shared__ float nrm2[FUSE_ZN ? 256 : 1];

    const int tid  = threadIdx.x;
    const int lane = tid & 63;
    const int wv   = tid >> 6;
    const int wm   = wv >> 1, wn = wv & 1;
    const int l16  = lane & 15, quad = lane >> 4;

    // ---- XCD-aware panel/col mapping ----
    const int P = (int)gridDim.x / NCB;
    int panel, colb;
    if (NCB == 1 || (P & 7) != 0) {
        panel = (int)blockIdx.x % P;
        colb  = (int)blockIdx.x / P;
    } else {
        int xcd = (int)blockIdx.x & 7;
        int loc = (int)blockIdx.x >> 3;
        panel = xcd * (P >> 3) + loc / NCB;
        colb  = loc % NCB;
    }
    const size_t m0 = (size_t)panel * 128;
    const int  n0  = colb * BN;
    const int  csw = quad ^ ((l16 >> 1) & 3);
    const int  nk  = K >> 5;

    auto stage = [&](int s, int k0) {
        if constexpr (CONV_A) {
            const float* Af = (const float*)Ap;
#pragma unroll
            for (int ii = 0; ii < 2; ++ii) {
                int u = (wv + ii * 4) * 64 + lane;
                int r = u >> 2;
                int kg = (u & 3) ^ ((r >> 1) & 3);
                const float* src = Af + (m0 + r) * K + k0 + kg * 8;
                float4 v0 = *(const float4*)src;
                float4 v1 = *(const float4*)(src + 4);
                bf16 t[8] = {(bf16)v0.x, (bf16)v0.y, (bf16)v0.z, (bf16)v0.w,
                             (bf16)v1.x, (bf16)v1.y, (bf16)v1.z, (bf16)v1.w};
                *(bf16x8*)&As[s][u * 8] = *(bf16x8*)t;
            }
        } else {
            const bf16* Ab = (const bf16*)Ap;
#pragma unroll
            for (int ii = 0; ii < 2; ++ii) {
                int i = wv + ii * 4;
                int u = i * 64 + lane;
                int r = u >> 2;
                int kg = (u & 3) ^ ((r >> 1) & 3);
                gld_lds16(Ab + (m0 + r) * K + k0 + kg * 8, &As[s][i * 512]);
            }
        }
#pragma unroll
        for (int ii = 0; ii < BN / 64; ++ii) {
            int i = wv + ii * 4;
            int u = i * 64 + lane;
            int r = u >> 2;
            int kg = (u & 3) ^ ((r >> 1) & 3);
            gld_lds16(WT + (size_t)(n0 + r) * K + k0 + kg * 8, &Bs[s][i * 512]);
        }
    };

    f32x4 acc[4][NT] = {};
    stage(0, 0);
    for (int kt = 0; kt < nk; ++kt) {
        __syncthreads();
        if (kt + 1 < nk) stage((kt + 1) & 1, (kt + 1) * 32);
        const bf16* as = As[kt & 1];
        const bf16* bs = Bs[kt & 1];
        bf16x8 af[4], bfr[NT];
#pragma unroll
        for (int i = 0; i < 4; ++i)
            af[i] = *(const bf16x8*)&as[(wm * 64 + i * 16 + l16) * 32 + csw * 8];
#pragma unroll
        for (int j = 0; j < NT; ++j)
            bfr[j] = *(const bf16x8*)&bs[(wn * (BN / 2) + j * 16 + l16) * 32 + csw * 8];
#pragma unroll
        for (int i = 0; i < 4; ++i)
#pragma unroll
            for (int j = 0; j < NT; ++j)
                acc[i][j] = __builtin_amdgcn_mfma_f32_16x16x32_bf16(af[i], bfr[j], acc[i][j], 0, 0, 0);
    }

    if constexpr (FUSE_ZN) {
        float vv[4][2][4];
        float pp[4][4];
#pragma unroll
        for (int i = 0; i < 4; ++i)
#pragma unroll
            for (int r = 0; r < 4; ++r) {
                float s = 0.f;
#pragma unroll
                for (int j = 0; j < 2; ++j) {
                    int col = n0 + wn * 32 + j * 16 + l16;
                    float v = acc[i][j][r] + shift[col];
                    vv[i][j][r] = v;
                    s = fmaf(v, v, s);
                }
                pp[i][r] = s;
            }
#pragma unroll
        for (int off = 1; off < 16; off <<= 1)
#pragma unroll
            for (int i = 0; i < 4; ++i)
#pragma unroll
                for (int r = 0; r < 4; ++r)
                    pp[i][r] += __shfl_xor(pp[i][r], off, 64);
        if (l16 == 0) {
#pragma unroll
            for (int i = 0; i < 4; ++i)
#pragma unroll
                for (int r = 0; r < 4; ++r)
                    nrm2[wn * 128 + wm * 64 + i * 16 + quad * 4 + r] = pp[i][r];
        }
        __syncthreads();
#pragma unroll
        for (int i = 0; i < 4; ++i)
#pragma unroll
            for (int r = 0; r < 4; ++r) {
                int rl = wm * 64 + i * 16 + quad * 4 + r;
                float s2 = nrm2[rl] + nrm2[128 + rl];
                float rn = 0.5f / fmaxf(sqrtf(s2), 1e-12f);
                size_t row = m0 + rl;
#pragma unroll
                for (int j = 0; j < 2; ++j) {
                    int col = n0 + wn * 32 + j * 16 + l16;
                    float v = vv[i][j][r];
                    ((bf16*)Cout)[row * 64 + col] = (bf16)v;
                    Zn[row * 64 + col] = (bf16)(v * rn);
                }
            }
    } else {
#pragma unroll
        for (int i = 0; i < 4; ++i) {
#pragma unroll
            for (int j = 0; j < NT; ++j) {
                int col = n0 + wn * (BN / 2) + j * 16 + l16;
                float sc = USE_SCALE ? scale[col] : 1.0f;
                float sh = shift[col];
#pragma unroll
                for (int r = 0; r < 4; ++r) {
                    size_t row = m0 + wm * 64 + i * 16 + quad * 4 + r;
                    float v = acc[i][j][r];
                    if (USE_SCALE) v *= sc;
                    v += sh;
                    if (RELU) v = fmaxf(v, 0.0f);
                    if (OUT_F32) ((float*)Cout)[row * (size_t)N + col] = v;
                    else         ((bf16*)Cout)[row * (size_t)N + col] = (bf16)v;
                }
            }
        }
    }
}

// ---------------------------------------------------------------------------
// prep_misc: blocks 0..1023 -> en (L2-normalized bf16 codebook);
// 1024..1039 -> zero counts; 1040 -> BN fold.
// ---------------------------------------------------------------------------
__global__ __launch_bounds__(256)
void prep_misc(const float* __restrict__ emb, bf16* __restrict__ en,
               unsigned int* __restrict__ counts,
               const float* __restrict__ b1, const float* __restrict__ g1,
               const float* __restrict__ be1, const float* __restrict__ rm1,
               const float* __restrict__ rv1,
               float* __restrict__ s1, float* __restrict__ sh1)
{
    const int bid = blockIdx.x;
    const int tid = threadIdx.x;
    if (bid < 1024) {
        int lane = tid & 63;
        int row = bid * 4 + (tid >> 6);
        float v = emb[(size_t)row * E_DIM + lane];
        float ss = v * v;
#pragma unroll
        for (int o = 32; o > 0; o >>= 1) ss += __shfl_xor(ss, o, 64);
        float n = fmaxf(sqrtf(ss), 1e-12f);
        en[(size_t)row * E_DIM + lane] = (bf16)(v / n);
    } else if (bid < 1040) {
        counts[(bid - 1024) * 256 + tid] = 0u;
    } else {
        for (int j = tid; j < H_DIM; j += 256) {
            float s = g1[j] * (1.0f / sqrtf(rv1[j] + 1e-5f));
            s1[j] = s;
            sh1[j] = (b1[j] - rm1[j]) * s + be1[j];
        }
    }
}

// ---------------------------------------------------------------------------
// All 8 weight transposes: 64x64 LDS tiles, coalesced both directions.
// ---------------------------------------------------------------------------
struct TranspArgs { const float* s[8]; bf16* d[8]; };

__global__ __launch_bounds__(256)
void transp_all(TranspArgs a)
{
    constexpr int KS[8]  = {128, 512, 512, 256,  64, 256, 512, 512};
    constexpr int NS[8]  = {512, 512, 256,  64, 256, 512, 512, 128};
    constexpr int CUM[9] = {0, 16, 80, 112, 116, 120, 152, 216, 232};
    __shared__ float T[64][65];

    int bid = blockIdx.x;
    int seg = 0;
#pragma unroll
    for (int s = 0; s < 8; ++s)
        if (bid >= CUM[s + 1]) seg = s + 1;
    const int bt = bid - CUM[seg];
    const int K = KS[seg], N = NS[seg];
    const int tiles_n = N / 64;
    const int k0 = (bt / tiles_n) * 64;
    const int n0 = (bt % tiles_n) * 64;
    const float* src = a.s[seg];
    bf16* dst = a.d[seg];

    const int tid = threadIdx.x;
    const int rr = tid >> 6, cc = tid & 63;
#pragma unroll
    for (int p = 0; p < 16; ++p) {
        int row = p * 4 + rr;
        T[row][cc] = src[(size_t)(k0 + row) * N + n0 + cc];
    }
    __syncthreads();
#pragma unroll
    for (int p = 0; p < 16; ++p) {
        int row = p * 4 + rr;
        dst[(size_t)(n0 + row) * K + k0 + cc] = (bf16)T[cc][row];
    }
}

// ---------------------------------------------------------------------------
// vq_all: per 64-row block (4 waves, 256 threads).
// R6's transposed mapping (wave owns a 32-code slice, scans all 64 rows in
// registers) taken to its conclusion: NO LDS staging, NO barriers in the
// argmin loop. Each wave streams its codebook slice DIRECTLY from L2 into
// registers (4x global_load_dwordx4 per tile), register double-buffered
// (named bufA/bufB, unroll-by-2, static indices). The per-tile
// barrier+vmcnt(0) cycle — measured at ~5400cyc/iter vs ~1100cyc issue —
// is gone. L2 traffic unchanged (each wave reads its slice exactly once).
//  1) argmin via MFMA (packed-uint (score|inv) argmax),
//  2) cross-wave combine via red[] scratch (barrier #1), packed-u8 LDS
//     histogram (R5-proven),
//  3) post: sumsq -> psum, x_recon scatter, global count atomics at end.
// ---------------------------------------------------------------------------
__global__ __launch_bounds__(256, 4)
void vq_all(const bf16* __restrict__ zn, const bf16* __restrict__ zb,
            const bf16* __restrict__ en, const float* __restrict__ emb,
            const float* __restrict__ XR, float* __restrict__ xout,
            unsigned int* __restrict__ counts, float* __restrict__ psum, int gb0)
{
    __shared__ unsigned hcnt[K_CODES / 4];   // 4 x u8 per word
    __shared__ int idxs[64];
    __shared__ float red[256];               // reused: u32 wave-best, then f32 reduce
    const int tid = threadIdx.x;
    const int lane = tid & 63;
    const int wv = tid >> 6;
    const int l16 = lane & 15, quad = lane >> 4;
    const long r0 = (long)blockIdx.x * 64;

    // A-fragments for ALL 64 rows of this block (rows are block-shared;
    // codes are wave-private). 8 x bf16x8 = 32 VGPRs.
    bf16x8 a0[4], a1[4];
#pragma unroll
    for (int rg = 0; rg < 4; ++rg) {
        long arow = r0 + rg * 16 + l16;
        a0[rg] = *(const bf16x8*)&zn[arow * E_DIM + quad * 8];
        a1[rg] = *(const bf16x8*)&zn[arow * E_DIM + 32 + quad * 8];
    }

    for (int j = tid; j < K_CODES / 4; j += 256) hcnt[j] = 0u;

    unsigned best[4][4];
#pragma unroll
    for (int rg = 0; rg < 4; ++rg)
#pragma unroll
        for (int r = 0; r < 4; ++r) best[rg][r] = 0u;
    const unsigned MASKHI = 0xFFFFF000u;

    // B-slice loader: logical layout en[code][64] bf16 (128 B/row).
    // lane (l16,quad): code row = c0 + wv*32 + cg*16 + l16;
    //   b0 = en[row][quad*8 .. +7], b1 = en[row][32+quad*8 .. +7].
    auto loadB = [&](int c0, bf16x8* d) {
        const bf16* p0 = en + (size_t)(c0 + wv * 32 + l16) * 64 + quad * 8;
        d[0] = *(const bf16x8*)p0;          // cg0 b0
        d[1] = *(const bf16x8*)(p0 + 32);   // cg0 b1
        const bf16* p1 = p0 + 16 * 64;      // +16 code rows
        d[2] = *(const bf16x8*)p1;          // cg1 b0
        d[3] = *(const bf16x8*)(p1 + 32);   // cg1 b1
    };
    auto computeT = [&](int c0, const bf16x8* b) {
#pragma unroll
        for (int cg = 0; cg < 2; ++cg) {
            unsigned inv = (unsigned)(4095 - (c0 + wv * 32 + cg * 16 + l16));
#pragma unroll
            for (int rg = 0; rg < 4; ++rg) {
                f32x4 acc = {1.5f, 1.5f, 1.5f, 1.5f};
                acc = __builtin_amdgcn_mfma_f32_16x16x32_bf16(a0[rg], b[cg * 2], acc, 0, 0, 0);
                acc = __builtin_amdgcn_mfma_f32_16x16x32_bf16(a1[rg], b[cg * 2 + 1], acc, 0, 0, 0);
#pragma unroll
                for (int r = 0; r < 4; ++r) {
                    unsigned pk = (__float_as_uint(acc[r]) & MASKHI) | inv;
                    best[rg][r] = best[rg][r] > pk ? best[rg][r] : pk;
                }
            }
        }
    };

    bf16x8 bA[4], bB[4];
    loadB(0, bA);
    loadB(128, bB);
    for (int c0 = 0; c0 < K_CODES; c0 += 256) {
        computeT(c0, bA);
        if (c0 + 256 < K_CODES) loadB(c0 + 256, bA);
        computeT(c0 + 128, bB);
        if (c0 + 384 < K_CODES) loadB(c0 + 384, bB);
    }

    // reduce across the 16 code-lanes (l16) for each of the 16 (rg,r) rows
#pragma unroll
    for (int off = 1; off < 16; off <<= 1) {
#pragma unroll
        for (int rg = 0; rg < 4; ++rg)
#pragma unroll
            for (int r = 0; r < 4; ++r) {
                unsigned o = (unsigned)__shfl_xor((int)best[rg][r], off, 64);
                best[rg][r] = best[rg][r] > o ? best[rg][r] : o;
            }
    }
    // per-wave per-row candidates -> LDS (red[] reused as u32 scratch)
    if (l16 == 0) {
        unsigned* wbest = (unsigned*)red;
#pragma unroll
        for (int rg = 0; rg < 4; ++rg)
#pragma unroll
            for (int r = 0; r < 4; ++r)
                wbest[wv * 64 + rg * 16 + quad * 4 + r] = best[rg][r];
    }
    __syncthreads();
    if (tid < 64) {
        const unsigned* wbest = (const unsigned*)red;
        unsigned m0 = wbest[tid],       m1 = wbest[64 + tid];
        unsigned m2 = wbest[128 + tid], m3 = wbest[192 + tid];
        unsigned m = m0 > m1 ? m0 : m1;
        unsigned n = m2 > m3 ? m2 : m3;
        m = m > n ? m : n;
        int b = 4095 - (int)(m & 0xFFFu);
        idxs[tid] = b;
        atomicAdd(&hcnt[b >> 2], 1u << ((b & 3) * 8));
    }
    __syncthreads();

    // post phase: wave wv handles rows wv, wv+4, ...
    float local = 0.f;
#pragma unroll 4
    for (int i = 0; i < 16; ++i) {
        int rl = wv + 4 * i;
        long row = r0 + rl;
        int id = idxs[rl] & (K_CODES - 1);
        float qv = emb[(size_t)id * E_DIM + lane];
        float zv = (float)zb[row * E_DIM + lane];
        float d = qv - zv;
        local = fmaf(d, d, local);
        float2 xv = *(const float2*)(XR + (size_t)id * D_IN + 2 * lane);
        float* dst = xout + (size_t)row * D_IN + 2 * lane;
        dst[0] = xv.x;
        dst[1] = xv.y;
    }
    red[tid] = local;
    __syncthreads();
    for (int s = 128; s > 0; s >>= 1) {
        if (tid < s) red[tid] += red[tid + s];
        __syncthreads();
    }
    if (tid == 0) psum[gb0 + blockIdx.x] = red[0];
    for (int j = tid; j < K_CODES / 4; j += 256) {
        unsigned w = hcnt[j];
        if (w) {
#pragma unroll
            for (int k = 0; k < 4; ++k) {
                unsigned c = (w >> (k * 8)) & 255u;
                if (c) atomicAdd(&counts[j * 4 + k], c);
            }
        }
    }
}

// ---------------------------------------------------------------------------
__global__ __launch_bounds__(1024)
void finalize_k(const unsigned int* __restrict__ counts, const float* __restrict__ psum,
                float* __restrict__ out_loss, float* __restrict__ out_perp)
{
    __shared__ float red[1024];
    const int tid = threadIdx.x;
    red[tid] = psum[tid];
    __syncthreads();
    for (int s = 512; s > 0; s >>= 1) {
        if (tid < s) red[tid] += red[tid + s];
        __syncthreads();
    }
    if (tid == 0)
        out_loss[0] = 1.02f * (red[0] * (1.0f / ((float)B_ROWS * (float)E_DIM)));
    __syncthreads();
    float e = 0.f;
    for (int j = tid; j < K_CODES; j += 1024) {
        float pr = (float)counts[j] * (1.0f / (float)B_ROWS);
        e += pr * logf(pr + 1e-10f);
    }
    red[tid] = e;
    __syncthreads();
    for (int s = 512; s > 0; s >>= 1) {
        if (tid < s) red[tid] += red[tid + s];
        __syncthreads();
    }
    if (tid == 0) out_perp[0] = expf(-red[0]);
}

// ---------------------------------------------------------------------------
extern "C" void kernel_launch(void* const* d_in, const int* in_sizes, int n_in,
                              void* d_out, int out_size, void* d_ws, size_t ws_size,
                              hipStream_t stream)
{
    const float* x   = (const float*)d_in[0];
    const float* W1  = (const float*)d_in[1];
    const float* b1  = (const float*)d_in[2];
    const float* g1  = (const float*)d_in[3];
    const float* be1 = (const float*)d_in[4];
    const float* rm1 = (const float*)d_in[5];
    const float* rv1 = (const float*)d_in[6];
    const float* W2  = (const float*)d_in[7];
    const float* b2  = (const float*)d_in[8];
    const float* W3  = (const float*)d_in[9];
    const float* b3  = (const float*)d_in[10];
    const float* W4  = (const float*)d_in[11];
    const float* b4  = (const float*)d_in[12];
    const float* emb = (const float*)d_in[13];
    const float* Dw1 = (const float*)d_in[14];
    const float* db1 = (const float*)d_in[15];
    const float* Dw2 = (const float*)d_in[16];
    const float* db2 = (const float*)d_in[17];
    const float* Dw3 = (const float*)d_in[18];
    const float* db3 = (const float*)d_in[19];
    const float* Dw4 = (const float*)d_in[20];
    const float* db4 = (const float*)d_in[21];
    float* out = (float*)d_out;
    (void)in_sizes; (void)n_in;

    // ---- workspace carve-up (256B-aligned) ----
    char* p = (char*)d_ws;
    size_t off = 0;
    auto alloc = [&](size_t bytes) -> char* {
        char* r = p + off;
        off = (off + bytes + 255) & ~(size_t)255;
        return r;
    };
    bf16* en  = (bf16*)alloc((size_t)K_CODES * E_DIM * 2);
    bf16* W1T = (bf16*)alloc((size_t)D_IN * H_DIM * 2);
    bf16* W2T = (bf16*)alloc((size_t)H_DIM * H_DIM * 2);
    bf16* W3T = (bf16*)alloc((size_t)H_DIM * (H_DIM / 2) * 2);
    bf16* W4T = (bf16*)alloc((size_t)(H_DIM / 2) * E_DIM * 2);
    bf16* D1T = (bf16*)alloc((size_t)E_DIM * (H_DIM / 2) * 2);
    bf16* D2T = (bf16*)alloc((size_t)(H_DIM / 2) * H_DIM * 2);
    bf16* D3T = (bf16*)alloc((size_t)H_DIM * H_DIM * 2);
    bf16* D4T = (bf16*)alloc((size_t)H_DIM * D_IN * 2);
    float* s1  = (float*)alloc(H_DIM * 4);
    float* sh1 = (float*)alloc(H_DIM * 4);
    unsigned int* counts = (unsigned int*)alloc(K_CODES * 4);
    float* psum = (float*)alloc((B_ROWS / 64) * 4);
    // mini decoder-on-codebook buffers
    bf16*  XR1  = (bf16*)alloc((size_t)K_CODES * (H_DIM / 2) * 2);  // 4096x256
    bf16*  XR2  = (bf16*)alloc((size_t)K_CODES * H_DIM * 2);        // 4096x512
    bf16*  XR3  = (bf16*)alloc((size_t)K_CODES * H_DIM * 2);        // 4096x512
    float* XRcb = (float*)alloc((size_t)K_CODES * D_IN * 4);        // 4096x128 f32
    size_t fixed_bytes = off;

    // per-chunk: Xb CH*1024 + Yb CH*1024 + zb CH*128 + zn CH*128
    int CH = 128;
    for (int c = B_ROWS; c >= 128; c >>= 1) {
        if (fixed_bytes + (size_t)c * 2304 + 4096 <= ws_size) { CH = c; break; }
    }
    bf16* Xb = (bf16*)alloc((size_t)CH * H_DIM * 2);
    bf16* Yb = (bf16*)alloc((size_t)CH * H_DIM * 2);
    bf16* zb = (bf16*)alloc((size_t)CH * E_DIM * 2);
    bf16* zn = (bf16*)alloc((size_t)CH * E_DIM * 2);

    // ---- prep (once) ----
    prep_misc<<<1041, 256, 0, stream>>>(emb, en, counts, b1, g1, be1, rm1, rv1, s1, sh1);
    TranspArgs ta;
    ta.s[0] = W1;  ta.d[0] = W1T;
    ta.s[1] = W2;  ta.d[1] = W2T;
    ta.s[2] = W3;  ta.d[2] = W3T;
    ta.s[3] = W4;  ta.d[3] = W4T;
    ta.s[4] = Dw1; ta.d[4] = D1T;
    ta.s[5] = Dw2; ta.d[5] = D2T;
    ta.s[6] = Dw3; ta.d[6] = D3T;
    ta.s[7] = Dw4; ta.d[7] = D4T;
    transp_all<<<232, 256, 0, stream>>>(ta);

    dim3 blk(256);

    // ---- mini decoder chain on the 4096-row codebook (one-time) ----
    // XRcb[c] = dec(emb[c]); then x_recon[row] = XRcb[idx[row]] (q_ste == q
    // to ~1 ulp fp32, far below accepted tolerance).
    mfma_gemm<128,2,true ,false,false,true ,false><<<32 * 2, blk, 0, stream>>>(emb, D1T, nullptr, db1, XR1, nullptr, K_CODES, 256,  64);
    mfma_gemm<128,4,false,false,false,true ,false><<<32 * 4, blk, 0, stream>>>(XR1, D2T, nullptr, db2, XR2, nullptr, K_CODES, 512, 256);
    mfma_gemm<128,4,false,false,false,true ,false><<<32 * 4, blk, 0, stream>>>(XR2, D3T, nullptr, db3, XR3, nullptr, K_CODES, 512, 512);
    mfma_gemm<128,1,false,true ,false,false,false><<<32 * 1, blk, 0, stream>>>(XR3, D4T, nullptr, db4, XRcb, nullptr, K_CODES, 128, 512);

    for (int c0 = 0; c0 < B_ROWS; c0 += CH) {
        const int M = CH;
        const int P = M / 128;

        // encoder (W1 converts x fp32->bf16 in staging; W4 fused with zn)
        mfma_gemm<128,4,true ,false,true ,true ,false><<<P * 4, blk, 0, stream>>>(x + (size_t)c0 * D_IN, W1T, s1, sh1, Xb, nullptr, M, 512, 128);
        mfma_gemm<128,4,false,false,false,true ,false><<<P * 4, blk, 0, stream>>>(Xb, W2T, nullptr, b2, Yb, nullptr, M, 512, 512);
        mfma_gemm<128,2,false,false,false,true ,false><<<P * 2, blk, 0, stream>>>(Yb, W3T, nullptr, b3, Xb, nullptr, M, 256, 512);
        mfma_gemm< 64,1,false,false,false,false,true ><<<P * 1, blk, 0, stream>>>(Xb, W4T, nullptr, b4, zb, zn, M, 64, 256);

        // VQ: argmin + histogram + sumsq + x_recon scatter, one kernel
        vq_all<<<M / 64, 256, 0, stream>>>(zn, zb, en, emb, XRcb,
                                           out + 1 + (size_t)c0 * D_IN,
                                           counts, psum, c0 / 64);
    }

    finalize_k<<<1, 1024, 0, stream>>>(counts, psum, out, out + (out_size - 1));
}

// Round 8
// 402.805 us; speedup vs baseline: 1.2685x; 1.2685x over previous
//
#include <hip/hip_runtime.h>
#include <hip/hip_bf16.h>

#define B_ROWS 65536
#define D_IN   128
#define H_DIM  512
#define E_DIM  64
#define K_CODES 4096

typedef __bf16 bf16;
typedef __attribute__((ext_vector_type(8))) __bf16 bf16x8;
typedef __attribute__((ext_vector_type(4))) float f32x4;

// async global->LDS, 16 B per lane; LDS dest = wave-uniform base + lane*16
__device__ __forceinline__ void gld_lds16(const bf16* g, bf16* l)
{
    __builtin_amdgcn_global_load_lds((const __attribute__((address_space(1))) void*)g,
                                     (__attribute__((address_space(3))) void*)l,
                                     16, 0, 0);
}

// ---------------------------------------------------------------------------
// bf16 MFMA GEMM, BM=128, BK=32, single-barrier double-buffered K-loop.
// C[M,N] = act(A[M,K] @ W[K,N] (*scale) + shift).  WT = W^T [N][K].
// XCD-aware 1-D grid swizzle (same-panel col-blocks adjacent + XCD-pinned).
// LDS rows 32-wide unpadded, XOR k-group swizzle (2-way-only read phases).
// CONV_A: A is fp32, converted to bf16 during staging (VGPR path).
// FUSE_ZN (BN=64): also emit zn = 0.5 * z/||z||.
// ---------------------------------------------------------------------------
template<int BN, int NCB, bool CONV_A, bool OUT_F32, bool USE_SCALE, bool RELU, bool FUSE_ZN>
__global__ __launch_bounds__(256)
void mfma_gemm(const void* __restrict__ Ap, const bf16* __restrict__ WT,
               const float* __restrict__ scale, const float* __restrict__ shift,
               void* __restrict__ Cout, bf16* __restrict__ Zn,
               int M, int N, int K)
{
    constexpr int NT = BN / 32;
    __shared__ bf16 As[2][128 * 32];
    __shared__ bf16 Bs[2][BN * 32];
    __shared__ float nrm2[FUSE_ZN ? 256 : 1];

    const int tid  = threadIdx.x;
    const int lane = tid & 63;
    const int wv   = tid >> 6;
    const int wm   = wv >> 1, wn = wv & 1;
    const int l16  = lane & 15, quad = lane >> 4;

    // ---- XCD-aware panel/col mapping ----
    const int P = (int)gridDim.x / NCB;
    int panel, colb;
    if (NCB == 1 || (P & 7) != 0) {
        panel = (int)blockIdx.x % P;
        colb  = (int)blockIdx.x / P;
    } else {
        int xcd = (int)blockIdx.x & 7;
        int loc = (int)blockIdx.x >> 3;
        panel = xcd * (P >> 3) + loc / NCB;
        colb  = loc % NCB;
    }
    const size_t m0 = (size_t)panel * 128;
    const int  n0  = colb * BN;
    const int  csw = quad ^ ((l16 >> 1) & 3);
    const int  nk  = K >> 5;

    auto stage = [&](int s, int k0) {
        if constexpr (CONV_A) {
            const float* Af = (const float*)Ap;
#pragma unroll
            for (int ii = 0; ii < 2; ++ii) {
                int u = (wv + ii * 4) * 64 + lane;
                int r = u >> 2;
                int kg = (u & 3) ^ ((r >> 1) & 3);
                const float* src = Af + (m0 + r) * K + k0 + kg * 8;
                float4 v0 = *(const float4*)src;
                float4 v1 = *(const float4*)(src + 4);
                bf16 t[8] = {(bf16)v0.x, (bf16)v0.y, (bf16)v0.z, (bf16)v0.w,
                             (bf16)v1.x, (bf16)v1.y, (bf16)v1.z, (bf16)v1.w};
                *(bf16x8*)&As[s][u * 8] = *(bf16x8*)t;
            }
        } else {
            const bf16* Ab = (const bf16*)Ap;
#pragma unroll
            for (int ii = 0; ii < 2; ++ii) {
                int i = wv + ii * 4;
                int u = i * 64 + lane;
                int r = u >> 2;
                int kg = (u & 3) ^ ((r >> 1) & 3);
                gld_lds16(Ab + (m0 + r) * K + k0 + kg * 8, &As[s][i * 512]);
            }
        }
#pragma unroll
        for (int ii = 0; ii < BN / 64; ++ii) {
            int i = wv + ii * 4;
            int u = i * 64 + lane;
            int r = u >> 2;
            int kg = (u & 3) ^ ((r >> 1) & 3);
            gld_lds16(WT + (size_t)(n0 + r) * K + k0 + kg * 8, &Bs[s][i * 512]);
        }
    };

    f32x4 acc[4][NT] = {};
    stage(0, 0);
    for (int kt = 0; kt < nk; ++kt) {
        __syncthreads();
        if (kt + 1 < nk) stage((kt + 1) & 1, (kt + 1) * 32);
        const bf16* as = As[kt & 1];
        const bf16* bs = Bs[kt & 1];
        bf16x8 af[4], bfr[NT];
#pragma unroll
        for (int i = 0; i < 4; ++i)
            af[i] = *(const bf16x8*)&as[(wm * 64 + i * 16 + l16) * 32 + csw * 8];
#pragma unroll
        for (int j = 0; j < NT; ++j)
            bfr[j] = *(const bf16x8*)&bs[(wn * (BN / 2) + j * 16 + l16) * 32 + csw * 8];
#pragma unroll
        for (int i = 0; i < 4; ++i)
#pragma unroll
            for (int j = 0; j < NT; ++j)
                acc[i][j] = __builtin_amdgcn_mfma_f32_16x16x32_bf16(af[i], bfr[j], acc[i][j], 0, 0, 0);
    }

    if constexpr (FUSE_ZN) {
        float vv[4][2][4];
        float pp[4][4];
#pragma unroll
        for (int i = 0; i < 4; ++i)
#pragma unroll
            for (int r = 0; r < 4; ++r) {
                float s = 0.f;
#pragma unroll
                for (int j = 0; j < 2; ++j) {
                    int col = n0 + wn * 32 + j * 16 + l16;
                    float v = acc[i][j][r] + shift[col];
                    vv[i][j][r] = v;
                    s = fmaf(v, v, s);
                }
                pp[i][r] = s;
            }
#pragma unroll
        for (int off = 1; off < 16; off <<= 1)
#pragma unroll
            for (int i = 0; i < 4; ++i)
#pragma unroll
                for (int r = 0; r < 4; ++r)
                    pp[i][r] += __shfl_xor(pp[i][r], off, 64);
        if (l16 == 0) {
#pragma unroll
            for (int i = 0; i < 4; ++i)
#pragma unroll
                for (int r = 0; r < 4; ++r)
                    nrm2[wn * 128 + wm * 64 + i * 16 + quad * 4 + r] = pp[i][r];
        }
        __syncthreads();
#pragma unroll
        for (int i = 0; i < 4; ++i)
#pragma unroll
            for (int r = 0; r < 4; ++r) {
                int rl = wm * 64 + i * 16 + quad * 4 + r;
                float s2 = nrm2[rl] + nrm2[128 + rl];
                float rn = 0.5f / fmaxf(sqrtf(s2), 1e-12f);
                size_t row = m0 + rl;
#pragma unroll
                for (int j = 0; j < 2; ++j) {
                    int col = n0 + wn * 32 + j * 16 + l16;
                    float v = vv[i][j][r];
                    ((bf16*)Cout)[row * 64 + col] = (bf16)v;
                    Zn[row * 64 + col] = (bf16)(v * rn);
                }
            }
    } else {
#pragma unroll
        for (int i = 0; i < 4; ++i) {
#pragma unroll
            for (int j = 0; j < NT; ++j) {
                int col = n0 + wn * (BN / 2) + j * 16 + l16;
                float sc = USE_SCALE ? scale[col] : 1.0f;
                float sh = shift[col];
#pragma unroll
                for (int r = 0; r < 4; ++r) {
                    size_t row = m0 + wm * 64 + i * 16 + quad * 4 + r;
                    float v = acc[i][j][r];
                    if (USE_SCALE) v *= sc;
                    v += sh;
                    if (RELU) v = fmaxf(v, 0.0f);
                    if (OUT_F32) ((float*)Cout)[row * (size_t)N + col] = v;
                    else         ((bf16*)Cout)[row * (size_t)N + col] = (bf16)v;
                }
            }
        }
    }
}

// ---------------------------------------------------------------------------
// prep_misc: blocks 0..1023 -> en (L2-normalized bf16 codebook);
// 1024..1039 -> zero counts; 1040 -> BN fold.
// ---------------------------------------------------------------------------
__global__ __launch_bounds__(256)
void prep_misc(const float* __restrict__ emb, bf16* __restrict__ en,
               unsigned int* __restrict__ counts,
               const float* __restrict__ b1, const float* __restrict__ g1,
               const float* __restrict__ be1, const float* __restrict__ rm1,
               const float* __restrict__ rv1,
               float* __restrict__ s1, float* __restrict__ sh1)
{
    const int bid = blockIdx.x;
    const int tid = threadIdx.x;
    if (bid < 1024) {
        int lane = tid & 63;
        int row = bid * 4 + (tid >> 6);
        float v = emb[(size_t)row * E_DIM + lane];
        float ss = v * v;
#pragma unroll
        for (int o = 32; o > 0; o >>= 1) ss += __shfl_xor(ss, o, 64);
        float n = fmaxf(sqrtf(ss), 1e-12f);
        en[(size_t)row * E_DIM + lane] = (bf16)(v / n);
    } else if (bid < 1040) {
        counts[(bid - 1024) * 256 + tid] = 0u;
    } else {
        for (int j = tid; j < H_DIM; j += 256) {
            float s = g1[j] * (1.0f / sqrtf(rv1[j] + 1e-5f));
            s1[j] = s;
            sh1[j] = (b1[j] - rm1[j]) * s + be1[j];
        }
    }
}

// ---------------------------------------------------------------------------
// All 8 weight transposes: 64x64 LDS tiles, coalesced both directions.
// ---------------------------------------------------------------------------
struct TranspArgs { const float* s[8]; bf16* d[8]; };

__global__ __launch_bounds__(256)
void transp_all(TranspArgs a)
{
    constexpr int KS[8]  = {128, 512, 512, 256,  64, 256, 512, 512};
    constexpr int NS[8]  = {512, 512, 256,  64, 256, 512, 512, 128};
    constexpr int CUM[9] = {0, 16, 80, 112, 116, 120, 152, 216, 232};
    __shared__ float T[64][65];

    int bid = blockIdx.x;
    int seg = 0;
#pragma unroll
    for (int s = 0; s < 8; ++s)
        if (bid >= CUM[s + 1]) seg = s + 1;
    const int bt = bid - CUM[seg];
    const int K = KS[seg], N = NS[seg];
    const int tiles_n = N / 64;
    const int k0 = (bt / tiles_n) * 64;
    const int n0 = (bt % tiles_n) * 64;
    const float* src = a.s[seg];
    bf16* dst = a.d[seg];

    const int tid = threadIdx.x;
    const int rr = tid >> 6, cc = tid & 63;
#pragma unroll
    for (int p = 0; p < 16; ++p) {
        int row = p * 4 + rr;
        T[row][cc] = src[(size_t)(k0 + row) * N + n0 + cc];
    }
    __syncthreads();
#pragma unroll
    for (int p = 0; p < 16; ++p) {
        int row = p * 4 + rr;
        dst[(size_t)(n0 + row) * K + k0 + cc] = (bf16)T[cc][row];
    }
}

// ---------------------------------------------------------------------------
// vq_scan: barrier-free argmin scan, split by code quarter.
// grid = NRB row-blocks x 4 quarters (quarter = bid >> lgNRB). Each block:
// 64 rows (A in registers, R6 mapping) x 1024 codes (8 reg-double-buffered
// tiles streamed straight from L2; only en+zn traffic in flight -> no
// eviction pressure, unlike R7 where xout/XR gathers evicted en -> 364MB
// HBM fetch). Packed (score|inv) keys use GLOBAL code index, so quarter
// bests are comparable and tie-break (smallest index) is preserved.
// Output: pbest[row*4 + q] = packed best for that quarter.
// ---------------------------------------------------------------------------
__global__ __launch_bounds__(256, 4)
void vq_scan(const bf16* __restrict__ zn, const bf16* __restrict__ en,
             unsigned* __restrict__ pbest, int nrbm1, int lgnrb)
{
    __shared__ unsigned wbest[256];
    const int tid = threadIdx.x;
    const int lane = tid & 63;
    const int wv = tid >> 6;
    const int l16 = lane & 15, quad = lane >> 4;
    const int q  = (int)blockIdx.x >> lgnrb;       // code quarter 0..3
    const int rb = (int)blockIdx.x & nrbm1;
    const long r0 = (long)rb * 64;
    const int cq = q * 1024;

    // A-fragments for ALL 64 rows (rows block-shared, codes wave-private)
    bf16x8 a0[4], a1[4];
#pragma unroll
    for (int rg = 0; rg < 4; ++rg) {
        long arow = r0 + rg * 16 + l16;
        a0[rg] = *(const bf16x8*)&zn[arow * E_DIM + quad * 8];
        a1[rg] = *(const bf16x8*)&zn[arow * E_DIM + 32 + quad * 8];
    }

    unsigned best[4][4];
#pragma unroll
    for (int rg = 0; rg < 4; ++rg)
#pragma unroll
        for (int r = 0; r < 4; ++r) best[rg][r] = 0u;
    const unsigned MASKHI = 0xFFFFF000u;

    auto loadB = [&](int c0, bf16x8* d) {
        const bf16* p0 = en + (size_t)(c0 + wv * 32 + l16) * 64 + quad * 8;
        d[0] = *(const bf16x8*)p0;          // cg0, K 0..31
        d[1] = *(const bf16x8*)(p0 + 32);   // cg0, K 32..63
        const bf16* p1 = p0 + 16 * 64;      // +16 code rows
        d[2] = *(const bf16x8*)p1;          // cg1, K 0..31
        d[3] = *(const bf16x8*)(p1 + 32);   // cg1, K 32..63
    };
    auto computeT = [&](int c0, const bf16x8* b) {
#pragma unroll
        for (int cg = 0; cg < 2; ++cg) {
            unsigned inv = (unsigned)(4095 - (c0 + wv * 32 + cg * 16 + l16));
#pragma unroll
            for (int rg = 0; rg < 4; ++rg) {
                f32x4 acc = {1.5f, 1.5f, 1.5f, 1.5f};
                acc = __builtin_amdgcn_mfma_f32_16x16x32_bf16(a0[rg], b[cg * 2], acc, 0, 0, 0);
                acc = __builtin_amdgcn_mfma_f32_16x16x32_bf16(a1[rg], b[cg * 2 + 1], acc, 0, 0, 0);
#pragma unroll
                for (int r = 0; r < 4; ++r) {
                    unsigned pk = (__float_as_uint(acc[r]) & MASKHI) | inv;
                    best[rg][r] = best[rg][r] > pk ? best[rg][r] : pk;
                }
            }
        }
    };

    bf16x8 bA[4], bB[4];
    loadB(cq, bA);
    loadB(cq + 128, bB);
#pragma unroll
    for (int t = 0; t < 1024; t += 256) {
        computeT(cq + t, bA);
        if (t + 256 < 1024) loadB(cq + t + 256, bA);
        computeT(cq + t + 128, bB);
        if (t + 384 < 1024) loadB(cq + t + 384, bB);
    }

    // reduce across the 16 code-lanes (l16) for each (rg,r) row
#pragma unroll
    for (int off = 1; off < 16; off <<= 1) {
#pragma unroll
        for (int rg = 0; rg < 4; ++rg)
#pragma unroll
            for (int r = 0; r < 4; ++r) {
                unsigned o = (unsigned)__shfl_xor((int)best[rg][r], off, 64);
                best[rg][r] = best[rg][r] > o ? best[rg][r] : o;
            }
    }
    if (l16 == 0) {
#pragma unroll
        for (int rg = 0; rg < 4; ++rg)
#pragma unroll
            for (int r = 0; r < 4; ++r)
                wbest[wv * 64 + rg * 16 + quad * 4 + r] = best[rg][r];
    }
    __syncthreads();
    if (tid < 64) {
        unsigned m0 = wbest[tid],       m1 = wbest[64 + tid];
        unsigned m2 = wbest[128 + tid], m3 = wbest[192 + tid];
        unsigned m = m0 > m1 ? m0 : m1;
        unsigned n = m2 > m3 ? m2 : m3;
        m = m > n ? m : n;
        pbest[(r0 + tid) * 4 + q] = m;
    }
}

// ---------------------------------------------------------------------------
// vq_post: per 64-row block — combine 4 quarter-bests (uint4 load, max),
// then the R5-proven post phase: packed-u8 LDS histogram, sumsq -> psum,
// x_recon scatter from XRcb, global count atomics at kernel end.
// ---------------------------------------------------------------------------
__global__ __launch_bounds__(256)
void vq_post(const bf16* __restrict__ zb, const float* __restrict__ emb,
             const unsigned* __restrict__ pbest, const float* __restrict__ XR,
             float* __restrict__ xout, unsigned int* __restrict__ counts,
             float* __restrict__ psum, int gb0)
{
    __shared__ unsigned hcnt[K_CODES / 4];   // 4 x u8 per word
    __shared__ int idxs[64];
    __shared__ float red[256];
    const int tid = threadIdx.x;
    const int lane = tid & 63;
    const int wv = tid >> 6;
    const long r0 = (long)blockIdx.x * 64;

    for (int j = tid; j < K_CODES / 4; j += 256) hcnt[j] = 0u;
    __syncthreads();
    if (tid < 64) {
        uint4 pb = *(const uint4*)&pbest[(r0 + tid) * 4];
        unsigned m = pb.x > pb.y ? pb.x : pb.y;
        unsigned n = pb.z > pb.w ? pb.z : pb.w;
        m = m > n ? m : n;
        int b = 4095 - (int)(m & 0xFFFu);
        idxs[tid] = b;
        atomicAdd(&hcnt[b >> 2], 1u << ((b & 3) * 8));
    }
    __syncthreads();

    // post phase: wave wv handles rows wv, wv+4, ...
    float local = 0.f;
#pragma unroll 4
    for (int i = 0; i < 16; ++i) {
        int rl = wv + 4 * i;
        long row = r0 + rl;
        int id = idxs[rl] & (K_CODES - 1);
        float qv = emb[(size_t)id * E_DIM + lane];
        float zv = (float)zb[row * E_DIM + lane];
        float d = qv - zv;
        local = fmaf(d, d, local);
        float2 xv = *(const float2*)(XR + (size_t)id * D_IN + 2 * lane);
        float* dst = xout + (size_t)row * D_IN + 2 * lane;
        dst[0] = xv.x;
        dst[1] = xv.y;
    }
    red[tid] = local;
    __syncthreads();
    for (int s = 128; s > 0; s >>= 1) {
        if (tid < s) red[tid] += red[tid + s];
        __syncthreads();
    }
    if (tid == 0) psum[gb0 + blockIdx.x] = red[0];
    for (int j = tid; j < K_CODES / 4; j += 256) {
        unsigned w = hcnt[j];
        if (w) {
#pragma unroll
            for (int k = 0; k < 4; ++k) {
                unsigned c = (w >> (k * 8)) & 255u;
                if (c) atomicAdd(&counts[j * 4 + k], c);
            }
        }
    }
}

// ---------------------------------------------------------------------------
__global__ __launch_bounds__(1024)
void finalize_k(const unsigned int* __restrict__ counts, const float* __restrict__ psum,
                float* __restrict__ out_loss, float* __restrict__ out_perp)
{
    __shared__ float red[1024];
    const int tid = threadIdx.x;
    red[tid] = psum[tid];
    __syncthreads();
    for (int s = 512; s > 0; s >>= 1) {
        if (tid < s) red[tid] += red[tid + s];
        __syncthreads();
    }
    if (tid == 0)
        out_loss[0] = 1.02f * (red[0] * (1.0f / ((float)B_ROWS * (float)E_DIM)));
    __syncthreads();
    float e = 0.f;
    for (int j = tid; j < K_CODES; j += 1024) {
        float pr = (float)counts[j] * (1.0f / (float)B_ROWS);
        e += pr * logf(pr + 1e-10f);
    }
    red[tid] = e;
    __syncthreads();
    for (int s = 512; s > 0; s >>= 1) {
        if (tid < s) red[tid] += red[tid + s];
        __syncthreads();
    }
    if (tid == 0) out_perp[0] = expf(-red[0]);
}

// ---------------------------------------------------------------------------
extern "C" void kernel_launch(void* const* d_in, const int* in_sizes, int n_in,
                              void* d_out, int out_size, void* d_ws, size_t ws_size,
                              hipStream_t stream)
{
    const float* x   = (const float*)d_in[0];
    const float* W1  = (const float*)d_in[1];
    const float* b1  = (const float*)d_in[2];
    const float* g1  = (const float*)d_in[3];
    const float* be1 = (const float*)d_in[4];
    const float* rm1 = (const float*)d_in[5];
    const float* rv1 = (const float*)d_in[6];
    const float* W2  = (const float*)d_in[7];
    const float* b2  = (const float*)d_in[8];
    const float* W3  = (const float*)d_in[9];
    const float* b3  = (const float*)d_in[10];
    const float* W4  = (const float*)d_in[11];
    const float* b4  = (const float*)d_in[12];
    const float* emb = (const float*)d_in[13];
    const float* Dw1 = (const float*)d_in[14];
    const float* db1 = (const float*)d_in[15];
    const float* Dw2 = (const float*)d_in[16];
    const float* db2 = (const float*)d_in[17];
    const float* Dw3 = (const float*)d_in[18];
    const float* db3 = (const float*)d_in[19];
    const float* Dw4 = (const float*)d_in[20];
    const float* db4 = (const float*)d_in[21];
    float* out = (float*)d_out;
    (void)in_sizes; (void)n_in;

    // ---- workspace carve-up (256B-aligned) ----
    char* p = (char*)d_ws;
    size_t off = 0;
    auto alloc = [&](size_t bytes) -> char* {
        char* r = p + off;
        off = (off + bytes + 255) & ~(size_t)255;
        return r;
    };
    bf16* en  = (bf16*)alloc((size_t)K_CODES * E_DIM * 2);
    bf16* W1T = (bf16*)alloc((size_t)D_IN * H_DIM * 2);
    bf16* W2T = (bf16*)alloc((size_t)H_DIM * H_DIM * 2);
    bf16* W3T = (bf16*)alloc((size_t)H_DIM * (H_DIM / 2) * 2);
    bf16* W4T = (bf16*)alloc((size_t)(H_DIM / 2) * E_DIM * 2);
    bf16* D1T = (bf16*)alloc((size_t)E_DIM * (H_DIM / 2) * 2);
    bf16* D2T = (bf16*)alloc((size_t)(H_DIM / 2) * H_DIM * 2);
    bf16* D3T = (bf16*)alloc((size_t)H_DIM * H_DIM * 2);
    bf16* D4T = (bf16*)alloc((size_t)H_DIM * D_IN * 2);
    float* s1  = (float*)alloc(H_DIM * 4);
    float* sh1 = (float*)alloc(H_DIM * 4);
    unsigned int* counts = (unsigned int*)alloc(K_CODES * 4);
    float* psum = (float*)alloc((B_ROWS / 64) * 4);
    // mini decoder-on-codebook buffers
    bf16*  XR1  = (bf16*)alloc((size_t)K_CODES * (H_DIM / 2) * 2);  // 4096x256
    bf16*  XR2  = (bf16*)alloc((size_t)K_CODES * H_DIM * 2);        // 4096x512
    bf16*  XR3  = (bf16*)alloc((size_t)K_CODES * H_DIM * 2);        // 4096x512
    float* XRcb = (float*)alloc((size_t)K_CODES * D_IN * 4);        // 4096x128 f32
    size_t fixed_bytes = off;

    // per-chunk: Xb CH*1024 + Yb CH*1024 + zb CH*128 + zn CH*128
    int CH = 128;
    for (int c = B_ROWS; c >= 128; c >>= 1) {
        if (fixed_bytes + (size_t)c * 2304 + 4096 <= ws_size) { CH = c; break; }
    }
    bf16* Xb = (bf16*)alloc((size_t)CH * H_DIM * 2);
    bf16* Yb = (bf16*)alloc((size_t)CH * H_DIM * 2);
    bf16* zb = (bf16*)alloc((size_t)CH * E_DIM * 2);
    bf16* zn = (bf16*)alloc((size_t)CH * E_DIM * 2);
    // pbest aliases XR2 (4 MB, dead after the one-time mini decoder chain);
    // needs CH*16 B <= 4 MB (true for CH <= 262144).
    unsigned* pbest = (unsigned*)XR2;

    // ---- prep (once) ----
    prep_misc<<<1041, 256, 0, stream>>>(emb, en, counts, b1, g1, be1, rm1, rv1, s1, sh1);
    TranspArgs ta;
    ta.s[0] = W1;  ta.d[0] = W1T;
    ta.s[1] = W2;  ta.d[1] = W2T;
    ta.s[2] = W3;  ta.d[2] = W3T;
    ta.s[3] = W4;  ta.d[3] = W4T;
    ta.s[4] = Dw1; ta.d[4] = D1T;
    ta.s[5] = Dw2; ta.d[5] = D2T;
    ta.s[6] = Dw3; ta.d[6] = D3T;
    ta.s[7] = Dw4; ta.d[7] = D4T;
    transp_all<<<232, 256, 0, stream>>>(ta);

    dim3 blk(256);

    // ---- mini decoder chain on the 4096-row codebook (one-time) ----
    // XRcb[c] = dec(emb[c]); then x_recon[row] = XRcb[idx[row]] (q_ste == q
    // to ~1 ulp fp32, far below accepted tolerance).
    mfma_gemm<128,2,true ,false,false,true ,false><<<32 * 2, blk, 0, stream>>>(emb, D1T, nullptr, db1, XR1, nullptr, K_CODES, 256,  64);
    mfma_gemm<128,4,false,false,false,true ,false><<<32 * 4, blk, 0, stream>>>(XR1, D2T, nullptr, db2, XR2, nullptr, K_CODES, 512, 256);
    mfma_gemm<128,4,false,false,false,true ,false><<<32 * 4, blk, 0, stream>>>(XR2, D3T, nullptr, db3, XR3, nullptr, K_CODES, 512, 512);
    mfma_gemm<128,1,false,true ,false,false,false><<<32 * 1, blk, 0, stream>>>(XR3, D4T, nullptr, db4, XRcb, nullptr, K_CODES, 128, 512);

    for (int c0 = 0; c0 < B_ROWS; c0 += CH) {
        const int M = CH;
        const int P = M / 128;
        const int NRB = M / 64;
        int lg = 0; while ((1 << lg) < NRB) ++lg;

        // encoder (W1 converts x fp32->bf16 in staging; W4 fused with zn)
        mfma_gemm<128,4,true ,false,true ,true ,false><<<P * 4, blk, 0, stream>>>(x + (size_t)c0 * D_IN, W1T, s1, sh1, Xb, nullptr, M, 512, 128);
        mfma_gemm<128,4,false,false,false,true ,false><<<P * 4, blk, 0, stream>>>(Xb, W2T, nullptr, b2, Yb, nullptr, M, 512, 512);
        mfma_gemm<128,2,false,false,false,true ,false><<<P * 2, blk, 0, stream>>>(Yb, W3T, nullptr, b3, Xb, nullptr, M, 256, 512);
        mfma_gemm< 64,1,false,false,false,false,true ><<<P * 1, blk, 0, stream>>>(Xb, W4T, nullptr, b4, zb, zn, M, 64, 256);

        // VQ: barrier-free quarter scan, then combine + post
        vq_scan<<<NRB * 4, blk, 0, stream>>>(zn, en, pbest, NRB - 1, lg);
        vq_post<<<NRB, blk, 0, stream>>>(zb, emb, pbest, XRcb,
                                         out + 1 + (size_t)c0 * D_IN,
                                         counts, psum, c0 / 64);
    }

    finalize_k<<<1, 1024, 0, stream>>>(counts, psum, out, out + (out_size - 1));
}

// Round 9
// 386.019 us; speedup vs baseline: 1.3236x; 1.0435x over previous
//
#include <hip/hip_runtime.h>
#include <hip/hip_bf16.h>

#define B_ROWS 65536
#define D_IN   128
#define H_DIM  512
#define E_DIM  64
#define K_CODES 4096

typedef __bf16 bf16;
typedef __attribute__((ext_vector_type(8))) __bf16 bf16x8;
typedef __attribute__((ext_vector_type(4))) float f32x4;

// async global->LDS, 16 B per lane; LDS dest = wave-uniform base + lane*16
__device__ __forceinline__ void gld_lds16(const bf16* g, bf16* l)
{
    __builtin_amdgcn_global_load_lds((const __attribute__((address_space(1))) void*)g,
                                     (__attribute__((address_space(3))) void*)l,
                                     16, 0, 0);
}

// ---------------------------------------------------------------------------
// bf16 MFMA GEMM, BM=128, BK=32, single-barrier double-buffered K-loop.
// C[M,N] = act(A[M,K] @ W[K,N] (*scale) + shift).  WT = W^T [N][K].
// XCD-aware 1-D grid swizzle (same-panel col-blocks adjacent + XCD-pinned).
// LDS rows 32-wide unpadded, XOR k-group swizzle (2-way-only read phases).
// CONV_A: A is fp32, converted to bf16 during staging (VGPR path).
// FUSE_ZN (BN=64): also emit zn = 0.5 * z/||z||.
// ---------------------------------------------------------------------------
template<int BN, int NCB, bool CONV_A, bool OUT_F32, bool USE_SCALE, bool RELU, bool FUSE_ZN>
__global__ __launch_bounds__(256)
void mfma_gemm(const void* __restrict__ Ap, const bf16* __restrict__ WT,
               const float* __restrict__ scale, const float* __restrict__ shift,
               void* __restrict__ Cout, bf16* __restrict__ Zn,
               int M, int N, int K)
{
    constexpr int NT = BN / 32;
    __shared__ bf16 As[2][128 * 32];
    __shared__ bf16 Bs[2][BN * 32];
    __shared__ float nrm2[FUSE_ZN ? 256 : 1];

    const int tid  = threadIdx.x;
    const int lane = tid & 63;
    const int wv   = tid >> 6;
    const int wm   = wv >> 1, wn = wv & 1;
    const int l16  = lane & 15, quad = lane >> 4;

    // ---- XCD-aware panel/col mapping ----
    const int P = (int)gridDim.x / NCB;
    int panel, colb;
    if (NCB == 1 || (P & 7) != 0) {
        panel = (int)blockIdx.x % P;
        colb  = (int)blockIdx.x / P;
    } else {
        int xcd = (int)blockIdx.x & 7;
        int loc = (int)blockIdx.x >> 3;
        panel = xcd * (P >> 3) + loc / NCB;
        colb  = loc % NCB;
    }
    const size_t m0 = (size_t)panel * 128;
    const int  n0  = colb * BN;
    const int  csw = quad ^ ((l16 >> 1) & 3);
    const int  nk  = K >> 5;

    auto stage = [&](int s, int k0) {
        if constexpr (CONV_A) {
            const float* Af = (const float*)Ap;
#pragma unroll
            for (int ii = 0; ii < 2; ++ii) {
                int u = (wv + ii * 4) * 64 + lane;
                int r = u >> 2;
                int kg = (u & 3) ^ ((r >> 1) & 3);
                const float* src = Af + (m0 + r) * K + k0 + kg * 8;
                float4 v0 = *(const float4*)src;
                float4 v1 = *(const float4*)(src + 4);
                bf16 t[8] = {(bf16)v0.x, (bf16)v0.y, (bf16)v0.z, (bf16)v0.w,
                             (bf16)v1.x, (bf16)v1.y, (bf16)v1.z, (bf16)v1.w};
                *(bf16x8*)&As[s][u * 8] = *(bf16x8*)t;
            }
        } else {
            const bf16* Ab = (const bf16*)Ap;
#pragma unroll
            for (int ii = 0; ii < 2; ++ii) {
                int i = wv + ii * 4;
                int u = i * 64 + lane;
                int r = u >> 2;
                int kg = (u & 3) ^ ((r >> 1) & 3);
                gld_lds16(Ab + (m0 + r) * K + k0 + kg * 8, &As[s][i * 512]);
            }
        }
#pragma unroll
        for (int ii = 0; ii < BN / 64; ++ii) {
            int i = wv + ii * 4;
            int u = i * 64 + lane;
            int r = u >> 2;
            int kg = (u & 3) ^ ((r >> 1) & 3);
            gld_lds16(WT + (size_t)(n0 + r) * K + k0 + kg * 8, &Bs[s][i * 512]);
        }
    };

    f32x4 acc[4][NT] = {};
    stage(0, 0);
    for (int kt = 0; kt < nk; ++kt) {
        __syncthreads();
        if (kt + 1 < nk) stage((kt + 1) & 1, (kt + 1) * 32);
        const bf16* as = As[kt & 1];
        const bf16* bs = Bs[kt & 1];
        bf16x8 af[4], bfr[NT];
#pragma unroll
        for (int i = 0; i < 4; ++i)
            af[i] = *(const bf16x8*)&as[(wm * 64 + i * 16 + l16) * 32 + csw * 8];
#pragma unroll
        for (int j = 0; j < NT; ++j)
            bfr[j] = *(const bf16x8*)&bs[(wn * (BN / 2) + j * 16 + l16) * 32 + csw * 8];
#pragma unroll
        for (int i = 0; i < 4; ++i)
#pragma unroll
            for (int j = 0; j < NT; ++j)
                acc[i][j] = __builtin_amdgcn_mfma_f32_16x16x32_bf16(af[i], bfr[j], acc[i][j], 0, 0, 0);
    }

    if constexpr (FUSE_ZN) {
        float vv[4][2][4];
        float pp[4][4];
#pragma unroll
        for (int i = 0; i < 4; ++i)
#pragma unroll
            for (int r = 0; r < 4; ++r) {
                float s = 0.f;
#pragma unroll
                for (int j = 0; j < 2; ++j) {
                    int col = n0 + wn * 32 + j * 16 + l16;
                    float v = acc[i][j][r] + shift[col];
                    vv[i][j][r] = v;
                    s = fmaf(v, v, s);
                }
                pp[i][r] = s;
            }
#pragma unroll
        for (int off = 1; off < 16; off <<= 1)
#pragma unroll
            for (int i = 0; i < 4; ++i)
#pragma unroll
                for (int r = 0; r < 4; ++r)
                    pp[i][r] += __shfl_xor(pp[i][r], off, 64);
        if (l16 == 0) {
#pragma unroll
            for (int i = 0; i < 4; ++i)
#pragma unroll
                for (int r = 0; r < 4; ++r)
                    nrm2[wn * 128 + wm * 64 + i * 16 + quad * 4 + r] = pp[i][r];
        }
        __syncthreads();
#pragma unroll
        for (int i = 0; i < 4; ++i)
#pragma unroll
            for (int r = 0; r < 4; ++r) {
                int rl = wm * 64 + i * 16 + quad * 4 + r;
                float s2 = nrm2[rl] + nrm2[128 + rl];
                float rn = 0.5f / fmaxf(sqrtf(s2), 1e-12f);
                size_t row = m0 + rl;
#pragma unroll
                for (int j = 0; j < 2; ++j) {
                    int col = n0 + wn * 32 + j * 16 + l16;
                    float v = vv[i][j][r];
                    ((bf16*)Cout)[row * 64 + col] = (bf16)v;
                    Zn[row * 64 + col] = (bf16)(v * rn);
                }
            }
    } else {
#pragma unroll
        for (int i = 0; i < 4; ++i) {
#pragma unroll
            for (int j = 0; j < NT; ++j) {
                int col = n0 + wn * (BN / 2) + j * 16 + l16;
                float sc = USE_SCALE ? scale[col] : 1.0f;
                float sh = shift[col];
#pragma unroll
                for (int r = 0; r < 4; ++r) {
                    size_t row = m0 + wm * 64 + i * 16 + quad * 4 + r;
                    float v = acc[i][j][r];
                    if (USE_SCALE) v *= sc;
                    v += sh;
                    if (RELU) v = fmaxf(v, 0.0f);
                    if (OUT_F32) ((float*)Cout)[row * (size_t)N + col] = v;
                    else         ((bf16*)Cout)[row * (size_t)N + col] = (bf16)v;
                }
            }
        }
    }
}

// ---------------------------------------------------------------------------
// prep_misc: blocks 0..1023 -> en (L2-normalized bf16 codebook);
// 1024..1039 -> zero counts; 1040 -> BN fold.
// ---------------------------------------------------------------------------
__global__ __launch_bounds__(256)
void prep_misc(const float* __restrict__ emb, bf16* __restrict__ en,
               unsigned int* __restrict__ counts,
               const float* __restrict__ b1, const float* __restrict__ g1,
               const float* __restrict__ be1, const float* __restrict__ rm1,
               const float* __restrict__ rv1,
               float* __restrict__ s1, float* __restrict__ sh1)
{
    const int bid = blockIdx.x;
    const int tid = threadIdx.x;
    if (bid < 1024) {
        int lane = tid & 63;
        int row = bid * 4 + (tid >> 6);
        float v = emb[(size_t)row * E_DIM + lane];
        float ss = v * v;
#pragma unroll
        for (int o = 32; o > 0; o >>= 1) ss += __shfl_xor(ss, o, 64);
        float n = fmaxf(sqrtf(ss), 1e-12f);
        en[(size_t)row * E_DIM + lane] = (bf16)(v / n);
    } else if (bid < 1040) {
        counts[(bid - 1024) * 256 + tid] = 0u;
    } else {
        for (int j = tid; j < H_DIM; j += 256) {
            float s = g1[j] * (1.0f / sqrtf(rv1[j] + 1e-5f));
            s1[j] = s;
            sh1[j] = (b1[j] - rm1[j]) * s + be1[j];
        }
    }
}

// ---------------------------------------------------------------------------
// All 8 weight transposes: 64x64 LDS tiles, coalesced both directions.
// ---------------------------------------------------------------------------
struct TranspArgs { const float* s[8]; bf16* d[8]; };

__global__ __launch_bounds__(256)
void transp_all(TranspArgs a)
{
    constexpr int KS[8]  = {128, 512, 512, 256,  64, 256, 512, 512};
    constexpr int NS[8]  = {512, 512, 256,  64, 256, 512, 512, 128};
    constexpr int CUM[9] = {0, 16, 80, 112, 116, 120, 152, 216, 232};
    __shared__ float T[64][65];

    int bid = blockIdx.x;
    int seg = 0;
#pragma unroll
    for (int s = 0; s < 8; ++s)
        if (bid >= CUM[s + 1]) seg = s + 1;
    const int bt = bid - CUM[seg];
    const int K = KS[seg], N = NS[seg];
    const int tiles_n = N / 64;
    const int k0 = (bt / tiles_n) * 64;
    const int n0 = (bt % tiles_n) * 64;
    const float* src = a.s[seg];
    bf16* dst = a.d[seg];

    const int tid = threadIdx.x;
    const int rr = tid >> 6, cc = tid & 63;
#pragma unroll
    for (int p = 0; p < 16; ++p) {
        int row = p * 4 + rr;
        T[row][cc] = src[(size_t)(k0 + row) * N + n0 + cc];
    }
    __syncthreads();
#pragma unroll
    for (int p = 0; p < 16; ++p) {
        int row = p * 4 + rr;
        dst[(size_t)(n0 + row) * K + k0 + cc] = (bf16)T[cc][row];
    }
}

// ---------------------------------------------------------------------------
// vq_all: R6 structure (359us verified: LDS-staged, barrier-per-tile,
// transposed wave->code mapping) scaled on its proven lever — independent
// barrier groups per CU (3 grp=93us, 4 grp=71.6us). Now: 32 rows/block,
// 64-code tiles -> LDS ~21.5KB -> 7 blocks/CU resident (grid 2048).
// Per-tile issue halves (2 ds_read_b128, 4 MFMA/wave); barrier count
// doubles but per-barrier stall overlaps across 7 groups.
// pk packing uses the BFI pattern (x&M)|(inv&~M) -> v_bfi_b32 (2 VALU/score,
// bit-identical semantics, tie-break preserved).
// ---------------------------------------------------------------------------
__global__ __launch_bounds__(256, 4)
void vq_all(const bf16* __restrict__ zn, const bf16* __restrict__ zb,
            const bf16* __restrict__ en, const float* __restrict__ emb,
            const float* __restrict__ XR, float* __restrict__ xout,
            unsigned int* __restrict__ counts, float* __restrict__ psum, int gb0)
{
    __shared__ bf16 es[2][64 * 64];
    __shared__ unsigned hcnt[K_CODES / 4];   // 4 x u8 per word
    __shared__ int idxs[32];
    __shared__ float red[256];               // reused: u32 wave-best, then f32 reduce
    const int tid = threadIdx.x;
    const int lane = tid & 63;
    const int wv = tid >> 6;
    const int l16 = lane & 15, quad = lane >> 4;
    const long r0 = (long)blockIdx.x * 32;

    // A-fragments for ALL 32 rows of this block (rows block-shared, codes
    // wave-private). 4 x bf16x8 = 16 VGPRs.
    bf16x8 a0[2], a1[2];
#pragma unroll
    for (int rg = 0; rg < 2; ++rg) {
        long arow = r0 + rg * 16 + l16;
        a0[rg] = *(const bf16x8*)&zn[arow * E_DIM + quad * 8];
        a1[rg] = *(const bf16x8*)&zn[arow * E_DIM + 32 + quad * 8];
    }

    // stage one 64-code tile (8 KB): per wave 2 x gld_lds16
    auto stage = [&](int s, int c0) {
#pragma unroll
        for (int ii = 0; ii < 2; ++ii) {
            int i = wv + ii * 4;                 // 0..7
            int u = i * 64 + lane;               // 0..511
            int r = u >> 3;                      // code row 0..63
            int kg = (u & 7) ^ (r & 7);
            gld_lds16(en + (size_t)(c0 + r) * E_DIM + kg * 8, &es[s][i * 512]);
        }
    };

    for (int j = tid; j < K_CODES / 4; j += 256) hcnt[j] = 0u;

    unsigned best[2][4];
#pragma unroll
    for (int rg = 0; rg < 2; ++rg)
#pragma unroll
        for (int r = 0; r < 4; ++r) best[rg][r] = 0u;
    const unsigned MASKHI = 0xFFFFF000u;

    stage(0, 0);
    for (int kt = 0; kt < 64; ++kt) {
        __syncthreads();
        if (kt + 1 < 64) stage((kt + 1) & 1, (kt + 1) * 64);
        const bf16* e = es[kt & 1];
        int srow = wv * 16 + l16;                // wave's code within tile
        bf16x8 b0 = *(const bf16x8*)&e[srow * 64 + ((quad ^ (srow & 7)) * 8)];
        bf16x8 b1 = *(const bf16x8*)&e[srow * 64 + (((quad + 4) ^ (srow & 7)) * 8)];
        unsigned inv = (unsigned)(4095 - (kt * 64 + srow));
#pragma unroll
        for (int rg = 0; rg < 2; ++rg) {
            f32x4 acc = {1.5f, 1.5f, 1.5f, 1.5f};
            acc = __builtin_amdgcn_mfma_f32_16x16x32_bf16(a0[rg], b0, acc, 0, 0, 0);
            acc = __builtin_amdgcn_mfma_f32_16x16x32_bf16(a1[rg], b1, acc, 0, 0, 0);
#pragma unroll
            for (int r = 0; r < 4; ++r) {
                // BFI pattern: (score & M) | (inv & ~M) -> v_bfi_b32
                unsigned pk = (__float_as_uint(acc[r]) & MASKHI) | (inv & 0x00000FFFu);
                best[rg][r] = best[rg][r] > pk ? best[rg][r] : pk;
            }
        }
    }
    // reduce across the 16 code-lanes (l16) for each (rg,r) row
#pragma unroll
    for (int off = 1; off < 16; off <<= 1) {
#pragma unroll
        for (int rg = 0; rg < 2; ++rg)
#pragma unroll
            for (int r = 0; r < 4; ++r) {
                unsigned o = (unsigned)__shfl_xor((int)best[rg][r], off, 64);
                best[rg][r] = best[rg][r] > o ? best[rg][r] : o;
            }
    }
    // per-wave per-row candidates -> LDS (red[] reused as u32 scratch)
    if (l16 == 0) {
        unsigned* wbest = (unsigned*)red;
#pragma unroll
        for (int rg = 0; rg < 2; ++rg)
#pragma unroll
            for (int r = 0; r < 4; ++r)
                wbest[wv * 32 + rg * 16 + quad * 4 + r] = best[rg][r];
    }
    __syncthreads();
    if (tid < 32) {
        const unsigned* wbest = (const unsigned*)red;
        unsigned m0 = wbest[tid],      m1 = wbest[32 + tid];
        unsigned m2 = wbest[64 + tid], m3 = wbest[96 + tid];
        unsigned m = m0 > m1 ? m0 : m1;
        unsigned n = m2 > m3 ? m2 : m3;
        m = m > n ? m : n;
        int b = 4095 - (int)(m & 0xFFFu);
        idxs[tid] = b;
        atomicAdd(&hcnt[b >> 2], 1u << ((b & 3) * 8));
    }
    __syncthreads();

    // post phase: wave wv handles rows wv, wv+4, ...
    float local = 0.f;
#pragma unroll 4
    for (int i = 0; i < 8; ++i) {
        int rl = wv + 4 * i;
        long row = r0 + rl;
        int id = idxs[rl] & (K_CODES - 1);
        float qv = emb[(size_t)id * E_DIM + lane];
        float zv = (float)zb[row * E_DIM + lane];
        float d = qv - zv;
        local = fmaf(d, d, local);
        float2 xv = *(const float2*)(XR + (size_t)id * D_IN + 2 * lane);
        *(float2*)(xout + (size_t)row * D_IN + 2 * lane) = xv;
    }
    red[tid] = local;
    __syncthreads();
    for (int s = 128; s > 0; s >>= 1) {
        if (tid < s) red[tid] += red[tid + s];
        __syncthreads();
    }
    if (tid == 0) psum[gb0 + blockIdx.x] = red[0];
    for (int j = tid; j < K_CODES / 4; j += 256) {
        unsigned w = hcnt[j];
        if (w) {
#pragma unroll
            for (int k = 0; k < 4; ++k) {
                unsigned c = (w >> (k * 8)) & 255u;
                if (c) atomicAdd(&counts[j * 4 + k], c);
            }
        }
    }
}

// ---------------------------------------------------------------------------
__global__ __launch_bounds__(1024)
void finalize_k(const unsigned int* __restrict__ counts, const float* __restrict__ psum,
                float* __restrict__ out_loss, float* __restrict__ out_perp)
{
    __shared__ float red[1024];
    const int tid = threadIdx.x;
    red[tid] = psum[tid] + psum[tid + 1024];   // B_ROWS/32 = 2048 partials
    __syncthreads();
    for (int s = 512; s > 0; s >>= 1) {
        if (tid < s) red[tid] += red[tid + s];
        __syncthreads();
    }
    if (tid == 0)
        out_loss[0] = 1.02f * (red[0] * (1.0f / ((float)B_ROWS * (float)E_DIM)));
    __syncthreads();
    float e = 0.f;
    for (int j = tid; j < K_CODES; j += 1024) {
        float pr = (float)counts[j] * (1.0f / (float)B_ROWS);
        e += pr * logf(pr + 1e-10f);
    }
    red[tid] = e;
    __syncthreads();
    for (int s = 512; s > 0; s >>= 1) {
        if (tid < s) red[tid] += red[tid + s];
        __syncthreads();
    }
    if (tid == 0) out_perp[0] = expf(-red[0]);
}

// ---------------------------------------------------------------------------
extern "C" void kernel_launch(void* const* d_in, const int* in_sizes, int n_in,
                              void* d_out, int out_size, void* d_ws, size_t ws_size,
                              hipStream_t stream)
{
    const float* x   = (const float*)d_in[0];
    const float* W1  = (const float*)d_in[1];
    const float* b1  = (const float*)d_in[2];
    const float* g1  = (const float*)d_in[3];
    const float* be1 = (const float*)d_in[4];
    const float* rm1 = (const float*)d_in[5];
    const float* rv1 = (const float*)d_in[6];
    const float* W2  = (const float*)d_in[7];
    const float* b2  = (const float*)d_in[8];
    const float* W3  = (const float*)d_in[9];
    const float* b3  = (const float*)d_in[10];
    const float* W4  = (const float*)d_in[11];
    const float* b4  = (const float*)d_in[12];
    const float* emb = (const float*)d_in[13];
    const float* Dw1 = (const float*)d_in[14];
    const float* db1 = (const float*)d_in[15];
    const float* Dw2 = (const float*)d_in[16];
    const float* db2 = (const float*)d_in[17];
    const float* Dw3 = (const float*)d_in[18];
    const float* db3 = (const float*)d_in[19];
    const float* Dw4 = (const float*)d_in[20];
    const float* db4 = (const float*)d_in[21];
    float* out = (float*)d_out;
    (void)in_sizes; (void)n_in;

    // ---- workspace carve-up (256B-aligned) ----
    char* p = (char*)d_ws;
    size_t off = 0;
    auto alloc = [&](size_t bytes) -> char* {
        char* r = p + off;
        off = (off + bytes + 255) & ~(size_t)255;
        return r;
    };
    bf16* en  = (bf16*)alloc((size_t)K_CODES * E_DIM * 2);
    bf16* W1T = (bf16*)alloc((size_t)D_IN * H_DIM * 2);
    bf16* W2T = (bf16*)alloc((size_t)H_DIM * H_DIM * 2);
    bf16* W3T = (bf16*)alloc((size_t)H_DIM * (H_DIM / 2) * 2);
    bf16* W4T = (bf16*)alloc((size_t)(H_DIM / 2) * E_DIM * 2);
    bf16* D1T = (bf16*)alloc((size_t)E_DIM * (H_DIM / 2) * 2);
    bf16* D2T = (bf16*)alloc((size_t)(H_DIM / 2) * H_DIM * 2);
    bf16* D3T = (bf16*)alloc((size_t)H_DIM * H_DIM * 2);
    bf16* D4T = (bf16*)alloc((size_t)H_DIM * D_IN * 2);
    float* s1  = (float*)alloc(H_DIM * 4);
    float* sh1 = (float*)alloc(H_DIM * 4);
    unsigned int* counts = (unsigned int*)alloc(K_CODES * 4);
    float* psum = (float*)alloc((B_ROWS / 32) * 4);
    // mini decoder-on-codebook buffers
    bf16*  XR1  = (bf16*)alloc((size_t)K_CODES * (H_DIM / 2) * 2);  // 4096x256
    bf16*  XR2  = (bf16*)alloc((size_t)K_CODES * H_DIM * 2);        // 4096x512
    bf16*  XR3  = (bf16*)alloc((size_t)K_CODES * H_DIM * 2);        // 4096x512
    float* XRcb = (float*)alloc((size_t)K_CODES * D_IN * 4);        // 4096x128 f32
    size_t fixed_bytes = off;

    // per-chunk: Xb CH*1024 + Yb CH*1024 + zb CH*128 + zn CH*128
    int CH = 128;
    for (int c = B_ROWS; c >= 128; c >>= 1) {
        if (fixed_bytes + (size_t)c * 2304 + 4096 <= ws_size) { CH = c; break; }
    }
    bf16* Xb = (bf16*)alloc((size_t)CH * H_DIM * 2);
    bf16* Yb = (bf16*)alloc((size_t)CH * H_DIM * 2);
    bf16* zb = (bf16*)alloc((size_t)CH * E_DIM * 2);
    bf16* zn = (bf16*)alloc((size_t)CH * E_DIM * 2);

    // ---- prep (once) ----
    prep_misc<<<1041, 256, 0, stream>>>(emb, en, counts, b1, g1, be1, rm1, rv1, s1, sh1);
    TranspArgs ta;
    ta.s[0] = W1;  ta.d[0] = W1T;
    ta.s[1] = W2;  ta.d[1] = W2T;
    ta.s[2] = W3;  ta.d[2] = W3T;
    ta.s[3] = W4;  ta.d[3] = W4T;
    ta.s[4] = Dw1; ta.d[4] = D1T;
    ta.s[5] = Dw2; ta.d[5] = D2T;
    ta.s[6] = Dw3; ta.d[6] = D3T;
    ta.s[7] = Dw4; ta.d[7] = D4T;
    transp_all<<<232, 256, 0, stream>>>(ta);

    dim3 blk(256);

    // ---- mini decoder chain on the 4096-row codebook (one-time) ----
    // XRcb[c] = dec(emb[c]); then x_recon[row] = XRcb[idx[row]] (q_ste == q
    // to ~1 ulp fp32, far below accepted tolerance).
    mfma_gemm<128,2,true ,false,false,true ,false><<<32 * 2, blk, 0, stream>>>(emb, D1T, nullptr, db1, XR1, nullptr, K_CODES, 256,  64);
    mfma_gemm<128,4,false,false,false,true ,false><<<32 * 4, blk, 0, stream>>>(XR1, D2T, nullptr, db2, XR2, nullptr, K_CODES, 512, 256);
    mfma_gemm<128,4,false,false,false,true ,false><<<32 * 4, blk, 0, stream>>>(XR2, D3T, nullptr, db3, XR3, nullptr, K_CODES, 512, 512);
    mfma_gemm<128,1,false,true ,false,false,false><<<32 * 1, blk, 0, stream>>>(XR3, D4T, nullptr, db4, XRcb, nullptr, K_CODES, 128, 512);

    for (int c0 = 0; c0 < B_ROWS; c0 += CH) {
        const int M = CH;
        const int P = M / 128;

        // encoder (W1 converts x fp32->bf16 in staging; W4 fused with zn)
        mfma_gemm<128,4,true ,false,true ,true ,false><<<P * 4, blk, 0, stream>>>(x + (size_t)c0 * D_IN, W1T, s1, sh1, Xb, nullptr, M, 512, 128);
        mfma_gemm<128,4,false,false,false,true ,false><<<P * 4, blk, 0, stream>>>(Xb, W2T, nullptr, b2, Yb, nullptr, M, 512, 512);
        mfma_gemm<128,2,false,false,false,true ,false><<<P * 2, blk, 0, stream>>>(Yb, W3T, nullptr, b3, Xb, nullptr, M, 256, 512);
        mfma_gemm< 64,1,false,false,false,false,true ><<<P * 1, blk, 0, stream>>>(Xb, W4T, nullptr, b4, zb, zn, M, 64, 256);

        // VQ: argmin + histogram + sumsq + x_recon scatter, one kernel
        vq_all<<<M / 32, 256, 0, stream>>>(zn, zb, en, emb, XRcb,
                                           out + 1 + (size_t)c0 * D_IN,
                                           counts, psum, c0 / 32);
    }

    finalize_k<<<1, 1024, 0, stream>>>(counts, psum, out, out + (out_size - 1));
}

// Round 11
// 333.700 us; speedup vs baseline: 1.5312x; 1.1568x over previous
//
#include <hip/hip_runtime.h>
#include <hip/hip_bf16.h>

#define B_ROWS 65536
#define D_IN   128
#define H_DIM  512
#define E_DIM  64
#define K_CODES 4096

typedef __bf16 bf16;
typedef __attribute__((ext_vector_type(8))) __bf16 bf16x8;
typedef __attribute__((ext_vector_type(4))) float f32x4;

// async global->LDS, 16 B per lane; LDS dest = wave-uniform base + lane*16
__device__ __forceinline__ void gld_lds16(const bf16* g, bf16* l)
{
    __builtin_amdgcn_global_load_lds((const __attribute__((address_space(1))) void*)g,
                                     (__attribute__((address_space(3))) void*)l,
                                     16, 0, 0);
}

// ---------------------------------------------------------------------------
// bf16 MFMA GEMM, BM=128, BK=32, single-barrier double-buffered K-loop.
// (original template form — used for enc-G4 (FUSE_ZN) and mini-G4 (OUT_F32))
// ---------------------------------------------------------------------------
template<int BN, int NCB, bool CONV_A, bool OUT_F32, bool USE_SCALE, bool RELU, bool FUSE_ZN>
__global__ __launch_bounds__(256)
void mfma_gemm(const void* __restrict__ Ap, const bf16* __restrict__ WT,
               const float* __restrict__ scale, const float* __restrict__ shift,
               void* __restrict__ Cout, bf16* __restrict__ Zn,
               int M, int N, int K)
{
    constexpr int NT = BN / 32;
    __shared__ bf16 As[2][128 * 32];
    __shared__ bf16 Bs[2][BN * 32];
    __shared__ float nrm2[FUSE_ZN ? 256 : 1];

    const int tid  = threadIdx.x;
    const int lane = tid & 63;
    const int wv   = tid >> 6;
    const int wm   = wv >> 1, wn = wv & 1;
    const int l16  = lane & 15, quad = lane >> 4;

    const int P = (int)gridDim.x / NCB;
    int panel, colb;
    if (NCB == 1 || (P & 7) != 0) {
        panel = (int)blockIdx.x % P;
        colb  = (int)blockIdx.x / P;
    } else {
        int xcd = (int)blockIdx.x & 7;
        int loc = (int)blockIdx.x >> 3;
        panel = xcd * (P >> 3) + loc / NCB;
        colb  = loc % NCB;
    }
    const size_t m0 = (size_t)panel * 128;
    const int  n0  = colb * BN;
    const int  csw = quad ^ ((l16 >> 1) & 3);
    const int  nk  = K >> 5;

    auto stage = [&](int s, int k0) {
        if constexpr (CONV_A) {
            const float* Af = (const float*)Ap;
#pragma unroll
            for (int ii = 0; ii < 2; ++ii) {
                int u = (wv + ii * 4) * 64 + lane;
                int r = u >> 2;
                int kg = (u & 3) ^ ((r >> 1) & 3);
                const float* src = Af + (m0 + r) * K + k0 + kg * 8;
                float4 v0 = *(const float4*)src;
                float4 v1 = *(const float4*)(src + 4);
                bf16 t[8] = {(bf16)v0.x, (bf16)v0.y, (bf16)v0.z, (bf16)v0.w,
                             (bf16)v1.x, (bf16)v1.y, (bf16)v1.z, (bf16)v1.w};
                *(bf16x8*)&As[s][u * 8] = *(bf16x8*)t;
            }
        } else {
            const bf16* Ab = (const bf16*)Ap;
#pragma unroll
            for (int ii = 0; ii < 2; ++ii) {
                int i = wv + ii * 4;
                int u = i * 64 + lane;
                int r = u >> 2;
                int kg = (u & 3) ^ ((r >> 1) & 3);
                gld_lds16(Ab + (m0 + r) * K + k0 + kg * 8, &As[s][i * 512]);
            }
        }
#pragma unroll
        for (int ii = 0; ii < BN / 64; ++ii) {
            int i = wv + ii * 4;
            int u = i * 64 + lane;
            int r = u >> 2;
            int kg = (u & 3) ^ ((r >> 1) & 3);
            gld_lds16(WT + (size_t)(n0 + r) * K + k0 + kg * 8, &Bs[s][i * 512]);
        }
    };

    f32x4 acc[4][NT] = {};
    stage(0, 0);
    for (int kt = 0; kt < nk; ++kt) {
        __syncthreads();
        if (kt + 1 < nk) stage((kt + 1) & 1, (kt + 1) * 32);
        const bf16* as = As[kt & 1];
        const bf16* bs = Bs[kt & 1];
        bf16x8 af[4], bfr[NT];
#pragma unroll
        for (int i = 0; i < 4; ++i)
            af[i] = *(const bf16x8*)&as[(wm * 64 + i * 16 + l16) * 32 + csw * 8];
#pragma unroll
        for (int j = 0; j < NT; ++j)
            bfr[j] = *(const bf16x8*)&bs[(wn * (BN / 2) + j * 16 + l16) * 32 + csw * 8];
#pragma unroll
        for (int i = 0; i < 4; ++i)
#pragma unroll
            for (int j = 0; j < NT; ++j)
                acc[i][j] = __builtin_amdgcn_mfma_f32_16x16x32_bf16(af[i], bfr[j], acc[i][j], 0, 0, 0);
    }

    if constexpr (FUSE_ZN) {
        float vv[4][2][4];
        float pp[4][4];
#pragma unroll
        for (int i = 0; i < 4; ++i)
#pragma unroll
            for (int r = 0; r < 4; ++r) {
                float s = 0.f;
#pragma unroll
                for (int j = 0; j < 2; ++j) {
                    int col = n0 + wn * 32 + j * 16 + l16;
                    float v = acc[i][j][r] + shift[col];
                    vv[i][j][r] = v;
                    s = fmaf(v, v, s);
                }
                pp[i][r] = s;
            }
#pragma unroll
        for (int off = 1; off < 16; off <<= 1)
#pragma unroll
            for (int i = 0; i < 4; ++i)
#pragma unroll
                for (int r = 0; r < 4; ++r)
                    pp[i][r] += __shfl_xor(pp[i][r], off, 64);
        if (l16 == 0) {
#pragma unroll
            for (int i = 0; i < 4; ++i)
#pragma unroll
                for (int r = 0; r < 4; ++r)
                    nrm2[wn * 128 + wm * 64 + i * 16 + quad * 4 + r] = pp[i][r];
        }
        __syncthreads();
#pragma unroll
        for (int i = 0; i < 4; ++i)
#pragma unroll
            for (int r = 0; r < 4; ++r) {
                int rl = wm * 64 + i * 16 + quad * 4 + r;
                float s2 = nrm2[rl] + nrm2[128 + rl];
                float rn = 0.5f / fmaxf(sqrtf(s2), 1e-12f);
                size_t row = m0 + rl;
#pragma unroll
                for (int j = 0; j < 2; ++j) {
                    int col = n0 + wn * 32 + j * 16 + l16;
                    float v = vv[i][j][r];
                    ((bf16*)Cout)[row * 64 + col] = (bf16)v;
                    Zn[row * 64 + col] = (bf16)(v * rn);
                }
            }
    } else {
#pragma unroll
        for (int i = 0; i < 4; ++i) {
#pragma unroll
            for (int j = 0; j < NT; ++j) {
                int col = n0 + wn * (BN / 2) + j * 16 + l16;
                float sc = USE_SCALE ? scale[col] : 1.0f;
                float sh = shift[col];
#pragma unroll
                for (int r = 0; r < 4; ++r) {
                    size_t row = m0 + wm * 64 + i * 16 + quad * 4 + r;
                    float v = acc[i][j][r];
                    if (USE_SCALE) v *= sc;
                    v += sh;
                    if (RELU) v = fmaxf(v, 0.0f);
                    if (OUT_F32) ((float*)Cout)[row * (size_t)N + col] = v;
                    else         ((bf16*)Cout)[row * (size_t)N + col] = (bf16)v;
                }
            }
        }
    }
}

// ---------------------------------------------------------------------------
// mfma_gemm2: same proven loop, BN=128 fixed, but TWO runtime problem
// descriptors per dispatch — the mini decoder-on-codebook GEMMs (4096 rows,
// 64-128 blocks) ride as extra grid blocks inside the big encoder GEMMs
// instead of 3 serial under-occupied dispatches. NCB/P and scale are
// runtime (sc=1.0 when scale==nullptr; v*1.0f is bit-exact), math and
// block mapping identical to the template version.
// ---------------------------------------------------------------------------
struct GemmProb {
    const void* Ap; const bf16* WT;
    const float* scale; const float* shift;
    void* Cout;
    int N, K, NCB, nblk;   // nblk = (M/128)*NCB
};

template<bool CONV_A, bool RELU>
__global__ __launch_bounds__(256)
void mfma_gemm2(GemmProb pA, GemmProb pB)
{
    __shared__ bf16 As[2][128 * 32];
    __shared__ bf16 Bs[2][128 * 32];

    const int tid  = threadIdx.x;
    const int lane = tid & 63;
    const int wv   = tid >> 6;
    const int wm   = wv >> 1, wn = wv & 1;
    const int l16  = lane & 15, quad = lane >> 4;

    const bool second = (int)blockIdx.x >= pA.nblk;
    const GemmProb p = second ? pB : pA;
    const int bid = second ? (int)blockIdx.x - pA.nblk : (int)blockIdx.x;
    const int N = p.N, K = p.K, NCB = p.NCB;

    const int P = p.nblk / NCB;
    int panel, colb;
    if (NCB == 1 || (P & 7) != 0) {
        panel = bid % P;
        colb  = bid / P;
    } else {
        int xcd = bid & 7;
        int loc = bid >> 3;
        panel = xcd * (P >> 3) + loc / NCB;
        colb  = loc % NCB;
    }
    const size_t m0 = (size_t)panel * 128;
    const int  n0  = colb * 128;
    const int  csw = quad ^ ((l16 >> 1) & 3);
    const int  nk  = K >> 5;

    auto stage = [&](int s, int k0) {
        if constexpr (CONV_A) {
            const float* Af = (const float*)p.Ap;
#pragma unroll
            for (int ii = 0; ii < 2; ++ii) {
                int u = (wv + ii * 4) * 64 + lane;
                int r = u >> 2;
                int kg = (u & 3) ^ ((r >> 1) & 3);
                const float* src = Af + (m0 + r) * K + k0 + kg * 8;
                float4 v0 = *(const float4*)src;
                float4 v1 = *(const float4*)(src + 4);
                bf16 t[8] = {(bf16)v0.x, (bf16)v0.y, (bf16)v0.z, (bf16)v0.w,
                             (bf16)v1.x, (bf16)v1.y, (bf16)v1.z, (bf16)v1.w};
                *(bf16x8*)&As[s][u * 8] = *(bf16x8*)t;
            }
        } else {
            const bf16* Ab = (const bf16*)p.Ap;
#pragma unroll
            for (int ii = 0; ii < 2; ++ii) {
                int i = wv + ii * 4;
                int u = i * 64 + lane;
                int r = u >> 2;
                int kg = (u & 3) ^ ((r >> 1) & 3);
                gld_lds16(Ab + (m0 + r) * K + k0 + kg * 8, &As[s][i * 512]);
            }
        }
#pragma unroll
        for (int ii = 0; ii < 2; ++ii) {
            int i = wv + ii * 4;
            int u = i * 64 + lane;
            int r = u >> 2;
            int kg = (u & 3) ^ ((r >> 1) & 3);
            gld_lds16(p.WT + (size_t)(n0 + r) * K + k0 + kg * 8, &Bs[s][i * 512]);
        }
    };

    f32x4 acc[4][4] = {};
    stage(0, 0);
    for (int kt = 0; kt < nk; ++kt) {
        __syncthreads();
        if (kt + 1 < nk) stage((kt + 1) & 1, (kt + 1) * 32);
        const bf16* as = As[kt & 1];
        const bf16* bs = Bs[kt & 1];
        bf16x8 af[4], bfr[4];
#pragma unroll
        for (int i = 0; i < 4; ++i)
            af[i] = *(const bf16x8*)&as[(wm * 64 + i * 16 + l16) * 32 + csw * 8];
#pragma unroll
        for (int j = 0; j < 4; ++j)
            bfr[j] = *(const bf16x8*)&bs[(wn * 64 + j * 16 + l16) * 32 + csw * 8];
#pragma unroll
        for (int i = 0; i < 4; ++i)
#pragma unroll
            for (int j = 0; j < 4; ++j)
                acc[i][j] = __builtin_amdgcn_mfma_f32_16x16x32_bf16(af[i], bfr[j], acc[i][j], 0, 0, 0);
    }

#pragma unroll
    for (int i = 0; i < 4; ++i) {
#pragma unroll
        for (int j = 0; j < 4; ++j) {
            int col = n0 + wn * 64 + j * 16 + l16;
            float sc = p.scale ? p.scale[col] : 1.0f;
            float sh = p.shift[col];
#pragma unroll
            for (int r = 0; r < 4; ++r) {
                size_t row = m0 + wm * 64 + i * 16 + quad * 4 + r;
                float v = acc[i][j][r];
                v *= sc;
                v += sh;
                if (RELU) v = fmaxf(v, 0.0f);
                ((bf16*)p.Cout)[row * (size_t)N + col] = (bf16)v;
            }
        }
    }
}

// ---------------------------------------------------------------------------
// prep_transp: merged prep_misc + transp_all (both independent, input-only).
// blocks 0..1023 -> en; 1024..1039 -> zero counts; 1040 -> BN fold;
// 1041.. -> the 8 weight transposes.
// ---------------------------------------------------------------------------
struct TranspArgs { const float* s[8]; bf16* d[8]; };

__global__ __launch_bounds__(256)
void prep_transp(const float* __restrict__ emb, bf16* __restrict__ en,
                 unsigned int* __restrict__ counts,
                 const float* __restrict__ b1, const float* __restrict__ g1,
                 const float* __restrict__ be1, const float* __restrict__ rm1,
                 const float* __restrict__ rv1,
                 float* __restrict__ s1, float* __restrict__ sh1,
                 TranspArgs a)
{
    __shared__ float T[64][65];
    const int bid = blockIdx.x;
    const int tid = threadIdx.x;
    if (bid < 1024) {
        int lane = tid & 63;
        int row = bid * 4 + (tid >> 6);
        float v = emb[(size_t)row * E_DIM + lane];
        float ss = v * v;
#pragma unroll
        for (int o = 32; o > 0; o >>= 1) ss += __shfl_xor(ss, o, 64);
        float n = fmaxf(sqrtf(ss), 1e-12f);
        en[(size_t)row * E_DIM + lane] = (bf16)(v / n);
        return;
    }
    if (bid < 1040) {
        counts[(bid - 1024) * 256 + tid] = 0u;
        return;
    }
    if (bid == 1040) {
        for (int j = tid; j < H_DIM; j += 256) {
            float s = g1[j] * (1.0f / sqrtf(rv1[j] + 1e-5f));
            s1[j] = s;
            sh1[j] = (b1[j] - rm1[j]) * s + be1[j];
        }
        return;
    }
    // ---- transposes (bid-1041 in 0..231) ----
    constexpr int KS[8]  = {128, 512, 512, 256,  64, 256, 512, 512};
    constexpr int NS[8]  = {512, 512, 256,  64, 256, 512, 512, 128};
    constexpr int CUM[9] = {0, 16, 80, 112, 116, 120, 152, 216, 232};
    int tb = bid - 1041;
    int seg = 0;
#pragma unroll
    for (int s = 0; s < 8; ++s)
        if (tb >= CUM[s + 1]) seg = s + 1;
    const int bt = tb - CUM[seg];
    const int K = KS[seg], N = NS[seg];
    const int tiles_n = N / 64;
    const int k0 = (bt / tiles_n) * 64;
    const int n0 = (bt % tiles_n) * 64;
    const float* src = a.s[seg];
    bf16* dst = a.d[seg];

    const int rr = tid >> 6, cc = tid & 63;
#pragma unroll
    for (int pp = 0; pp < 16; ++pp) {
        int row = pp * 4 + rr;
        T[row][cc] = src[(size_t)(k0 + row) * N + n0 + cc];
    }
    __syncthreads();
#pragma unroll
    for (int pp = 0; pp < 16; ++pp) {
        int row = pp * 4 + rr;
        dst[(size_t)(n0 + row) * K + k0 + cc] = (bf16)T[cc][row];
    }
}

// ---------------------------------------------------------------------------
// vq_all: R6-verified structure (71.6us): 64 rows/block, 128-code LDS tiles,
// transposed wave->code mapping (wave owns 32-code slice, scans all 64 rows
// in registers; 4 ds_read_b128/wave/tile), packed-u8 LDS histogram,
// global count atomics at kernel end. 4 blocks/CU — the measured optimum
// (3grp=93, 4grp=71.6, 7grp/2x-barriers=99, 2grp=143).
// ---------------------------------------------------------------------------
__global__ __launch_bounds__(256, 4)
void vq_all(const bf16* __restrict__ zn, const bf16* __restrict__ zb,
            const bf16* __restrict__ en, const float* __restrict__ emb,
            const float* __restrict__ XR, float* __restrict__ xout,
            unsigned int* __restrict__ counts, float* __restrict__ psum, int gb0)
{
    __shared__ bf16 es[2][128 * 64];
    __shared__ unsigned hcnt[K_CODES / 4];   // 4 x u8 per word
    __shared__ int idxs[64];
    __shared__ float red[256];               // reused: u32 wave-best, then f32 reduce
    const int tid = threadIdx.x;
    const int lane = tid & 63;
    const int wv = tid >> 6;
    const int l16 = lane & 15, quad = lane >> 4;
    const long r0 = (long)blockIdx.x * 64;

    // A-fragments for ALL 64 rows of this block (rows are block-shared;
    // codes are wave-private). 8 x bf16x8 = 32 VGPRs.
    bf16x8 a0[4], a1[4];
#pragma unroll
    for (int rg = 0; rg < 4; ++rg) {
        long arow = r0 + rg * 16 + l16;
        a0[rg] = *(const bf16x8*)&zn[arow * E_DIM + quad * 8];
        a1[rg] = *(const bf16x8*)&zn[arow * E_DIM + 32 + quad * 8];
    }

    auto stage = [&](int s, int c0) {
#pragma unroll
        for (int ii = 0; ii < 4; ++ii) {
            int i = wv + ii * 4;
            int u = i * 64 + lane;
            int r = u >> 3;
            int kg = (u & 7) ^ (r & 7);
            gld_lds16(en + (size_t)(c0 + r) * E_DIM + kg * 8, &es[s][i * 512]);
        }
    };

    for (int j = tid; j < K_CODES / 4; j += 256) hcnt[j] = 0u;

    unsigned best[4][4];
#pragma unroll
    for (int rg = 0; rg < 4; ++rg)
#pragma unroll
        for (int r = 0; r < 4; ++r) best[rg][r] = 0u;
    const unsigned MASKHI = 0xFFFFF000u;

    stage(0, 0);
    for (int c0 = 0; c0 < K_CODES; c0 += 128) {
        __syncthreads();
        if (c0 + 128 < K_CODES) stage(((c0 >> 7) + 1) & 1, c0 + 128);
        const bf16* e = es[(c0 >> 7) & 1];
#pragma unroll
        for (int cg = 0; cg < 2; ++cg) {
            int srow = wv * 32 + cg * 16 + l16;      // code row within tile
            bf16x8 b0 = *(const bf16x8*)&e[srow * 64 + ((quad ^ (srow & 7)) * 8)];
            bf16x8 b1 = *(const bf16x8*)&e[srow * 64 + (((quad + 4) ^ (srow & 7)) * 8)];
            unsigned inv = (unsigned)(4095 - (c0 + srow));
#pragma unroll
            for (int rg = 0; rg < 4; ++rg) {
                f32x4 acc = {1.5f, 1.5f, 1.5f, 1.5f};
                acc = __builtin_amdgcn_mfma_f32_16x16x32_bf16(a0[rg], b0, acc, 0, 0, 0);
                acc = __builtin_amdgcn_mfma_f32_16x16x32_bf16(a1[rg], b1, acc, 0, 0, 0);
#pragma unroll
                for (int r = 0; r < 4; ++r) {
                    unsigned pk = (__float_as_uint(acc[r]) & MASKHI) | inv;
                    best[rg][r] = best[rg][r] > pk ? best[rg][r] : pk;
                }
            }
        }
    }
    // reduce across the 16 code-lanes (l16) for each of the 16 (rg,r) rows
#pragma unroll
    for (int off = 1; off < 16; off <<= 1) {
#pragma unroll
        for (int rg = 0; rg < 4; ++rg)
#pragma unroll
            for (int r = 0; r < 4; ++r) {
                unsigned o = (unsigned)__shfl_xor((int)best[rg][r], off, 64);
                best[rg][r] = best[rg][r] > o ? best[rg][r] : o;
            }
    }
    // per-wave per-row candidates -> LDS (red[] reused as u32 scratch)
    if (l16 == 0) {
        unsigned* wbest = (unsigned*)red;
#pragma unroll
        for (int rg = 0; rg < 4; ++rg)
#pragma unroll
            for (int r = 0; r < 4; ++r)
                wbest[wv * 64 + rg * 16 + quad * 4 + r] = best[rg][r];
    }
    __syncthreads();
    if (tid < 64) {
        const unsigned* wbest = (const unsigned*)red;
        unsigned m0 = wbest[tid],       m1 = wbest[64 + tid];
        unsigned m2 = wbest[128 + tid], m3 = wbest[192 + tid];
        unsigned m = m0 > m1 ? m0 : m1;
        unsigned n = m2 > m3 ? m2 : m3;
        m = m > n ? m : n;
        int b = 4095 - (int)(m & 0xFFFu);
        idxs[tid] = b;
        atomicAdd(&hcnt[b >> 2], 1u << ((b & 3) * 8));
    }
    __syncthreads();

    // post phase: wave wv handles rows wv, wv+4, ...
    float local = 0.f;
#pragma unroll 4
    for (int i = 0; i < 16; ++i) {
        int rl = wv + 4 * i;
        long row = r0 + rl;
        int id = idxs[rl] & (K_CODES - 1);
        float qv = emb[(size_t)id * E_DIM + lane];
        float zv = (float)zb[row * E_DIM + lane];
        float d = qv - zv;
        local = fmaf(d, d, local);
        float2 xv = *(const float2*)(XR + (size_t)id * D_IN + 2 * lane);
        float* dst = xout + (size_t)row * D_IN + 2 * lane;
        dst[0] = xv.x;
        dst[1] = xv.y;
    }
    red[tid] = local;
    __syncthreads();
    for (int s = 128; s > 0; s >>= 1) {
        if (tid < s) red[tid] += red[tid + s];
        __syncthreads();
    }
    if (tid == 0) psum[gb0 + blockIdx.x] = red[0];
    for (int j = tid; j < K_CODES / 4; j += 256) {
        unsigned w = hcnt[j];
        if (w) {
#pragma unroll
            for (int k = 0; k < 4; ++k) {
                unsigned c = (w >> (k * 8)) & 255u;
                if (c) atomicAdd(&counts[j * 4 + k], c);
            }
        }
    }
}

// ---------------------------------------------------------------------------
__global__ __launch_bounds__(1024)
void finalize_k(const unsigned int* __restrict__ counts, const float* __restrict__ psum,
                float* __restrict__ out_loss, float* __restrict__ out_perp)
{
    __shared__ float red[1024];
    const int tid = threadIdx.x;
    red[tid] = psum[tid];
    __syncthreads();
    for (int s = 512; s > 0; s >>= 1) {
        if (tid < s) red[tid] += red[tid + s];
        __syncthreads();
    }
    if (tid == 0)
        out_loss[0] = 1.02f * (red[0] * (1.0f / ((float)B_ROWS * (float)E_DIM)));
    __syncthreads();
    float e = 0.f;
    for (int j = tid; j < K_CODES; j += 1024) {
        float pr = (float)counts[j] * (1.0f / (float)B_ROWS);
        e += pr * logf(pr + 1e-10f);
    }
    red[tid] = e;
    __syncthreads();
    for (int s = 512; s > 0; s >>= 1) {
        if (tid < s) red[tid] += red[tid + s];
        __syncthreads();
    }
    if (tid == 0) out_perp[0] = expf(-red[0]);
}

// ---------------------------------------------------------------------------
extern "C" void kernel_launch(void* const* d_in, const int* in_sizes, int n_in,
                              void* d_out, int out_size, void* d_ws, size_t ws_size,
                              hipStream_t stream)
{
    const float* x   = (const float*)d_in[0];
    const float* W1  = (const float*)d_in[1];
    const float* b1  = (const float*)d_in[2];
    const float* g1  = (const float*)d_in[3];
    const float* be1 = (const float*)d_in[4];
    const float* rm1 = (const float*)d_in[5];
    const float* rv1 = (const float*)d_in[6];
    const float* W2  = (const float*)d_in[7];
    const float* b2  = (const float*)d_in[8];
    const float* W3  = (const float*)d_in[9];
    const float* b3  = (const float*)d_in[10];
    const float* W4  = (const float*)d_in[11];
    const float* b4  = (const float*)d_in[12];
    const float* emb = (const float*)d_in[13];
    const float* Dw1 = (const float*)d_in[14];
    const float* db1 = (const float*)d_in[15];
    const float* Dw2 = (const float*)d_in[16];
    const float* db2 = (const float*)d_in[17];
    const float* Dw3 = (const float*)d_in[18];
    const float* db3 = (const float*)d_in[19];
    const float* Dw4 = (const float*)d_in[20];
    const float* db4 = (const float*)d_in[21];
    float* out = (float*)d_out;
    (void)in_sizes; (void)n_in;

    // ---- workspace carve-up (256B-aligned) ----
    char* p = (char*)d_ws;
    size_t off = 0;
    auto alloc = [&](size_t bytes) -> char* {
        char* r = p + off;
        off = (off + bytes + 255) & ~(size_t)255;
        return r;
    };
    bf16* en  = (bf16*)alloc((size_t)K_CODES * E_DIM * 2);
    bf16* W1T = (bf16*)alloc((size_t)D_IN * H_DIM * 2);
    bf16* W2T = (bf16*)alloc((size_t)H_DIM * H_DIM * 2);
    bf16* W3T = (bf16*)alloc((size_t)H_DIM * (H_DIM / 2) * 2);
    bf16* W4T = (bf16*)alloc((size_t)(H_DIM / 2) * E_DIM * 2);
    bf16* D1T = (bf16*)alloc((size_t)E_DIM * (H_DIM / 2) * 2);
    bf16* D2T = (bf16*)alloc((size_t)(H_DIM / 2) * H_DIM * 2);
    bf16* D3T = (bf16*)alloc((size_t)H_DIM * H_DIM * 2);
    bf16* D4T = (bf16*)alloc((size_t)H_DIM * D_IN * 2);
    float* s1  = (float*)alloc(H_DIM * 4);
    float* sh1 = (float*)alloc(H_DIM * 4);
    unsigned int* counts = (unsigned int*)alloc(K_CODES * 4);
    float* psum = (float*)alloc((B_ROWS / 64) * 4);
    // mini decoder-on-codebook buffers
    bf16*  XR1  = (bf16*)alloc((size_t)K_CODES * (H_DIM / 2) * 2);  // 4096x256
    bf16*  XR2  = (bf16*)alloc((size_t)K_CODES * H_DIM * 2);        // 4096x512
    bf16*  XR3  = (bf16*)alloc((size_t)K_CODES * H_DIM * 2);        // 4096x512
    float* XRcb = (float*)alloc((size_t)K_CODES * D_IN * 4);        // 4096x128 f32
    size_t fixed_bytes = off;

    // per-chunk: Xb CH*1024 + Yb CH*1024 + zb CH*128 + zn CH*128
    int CH = 128;
    for (int c = B_ROWS; c >= 128; c >>= 1) {
        if (fixed_bytes + (size_t)c * 2304 + 4096 <= ws_size) { CH = c; break; }
    }
    bf16* Xb = (bf16*)alloc((size_t)CH * H_DIM * 2);
    bf16* Yb = (bf16*)alloc((size_t)CH * H_DIM * 2);
    bf16* zb = (bf16*)alloc((size_t)CH * E_DIM * 2);
    bf16* zn = (bf16*)alloc((size_t)CH * E_DIM * 2);

    // ---- prep + transposes, one dispatch ----
    TranspArgs ta;
    ta.s[0] = W1;  ta.d[0] = W1T;
    ta.s[1] = W2;  ta.d[1] = W2T;
    ta.s[2] = W3;  ta.d[2] = W3T;
    ta.s[3] = W4;  ta.d[3] = W4T;
    ta.s[4] = Dw1; ta.d[4] = D1T;
    ta.s[5] = Dw2; ta.d[5] = D2T;
    ta.s[6] = Dw3; ta.d[6] = D3T;
    ta.s[7] = Dw4; ta.d[7] = D4T;
    prep_transp<<<1041 + 232, 256, 0, stream>>>(emb, en, counts, b1, g1, be1, rm1, rv1, s1, sh1, ta);

    dim3 blk(256);
    const GemmProb NONE = {nullptr, nullptr, nullptr, nullptr, nullptr, 0, 0, 1, 0};

    for (int c0 = 0; c0 < B_ROWS; c0 += CH) {
        const int M = CH;
        const int P = M / 128;
        const bool z = (c0 == 0);   // zip the one-time mini decoder chain
                                    // (XRcb[c]=dec(emb[c])) into chunk 0's
                                    // encoder dispatches as extra blocks

        GemmProb e1 = {x + (size_t)c0 * D_IN, W1T, s1, sh1, Xb, 512, 128, 4, P * 4};
        GemmProb m1 = {emb, D1T, nullptr, db1, XR1, 256, 64, 2, 64};
        mfma_gemm2<true , true><<<e1.nblk + (z ? m1.nblk : 0), blk, 0, stream>>>(e1, z ? m1 : NONE);

        GemmProb e2 = {Xb, W2T, nullptr, b2, Yb, 512, 512, 4, P * 4};
        GemmProb m2 = {XR1, D2T, nullptr, db2, XR2, 512, 256, 4, 128};
        mfma_gemm2<false, true><<<e2.nblk + (z ? m2.nblk : 0), blk, 0, stream>>>(e2, z ? m2 : NONE);

        GemmProb e3 = {Yb, W3T, nullptr, b3, Xb, 256, 512, 2, P * 2};
        GemmProb m3 = {XR2, D3T, nullptr, db3, XR3, 512, 512, 4, 128};
        mfma_gemm2<false, true><<<e3.nblk + (z ? m3.nblk : 0), blk, 0, stream>>>(e3, z ? m3 : NONE);

        if (z)
            mfma_gemm<128,1,false,true ,false,false,false><<<32, blk, 0, stream>>>(XR3, D4T, nullptr, db4, XRcb, nullptr, K_CODES, 128, 512);
        mfma_gemm< 64,1,false,false,false,false,true ><<<P * 1, blk, 0, stream>>>(Xb, W4T, nullptr, b4, zb, zn, M, 64, 256);

        // VQ: argmin + histogram + sumsq + x_recon scatter, one kernel
        vq_all<<<M / 64, 256, 0, stream>>>(zn, zb, en, emb, XRcb,
                                           out + 1 + (size_t)c0 * D_IN,
                                           counts, psum, c0 / 64);
    }

    finalize_k<<<1, 1024, 0, stream>>>(counts, psum, out, out + (out_size - 1));
}

// Round 12
// 333.027 us; speedup vs baseline: 1.5343x; 1.0020x over previous
//
#include <hip/hip_runtime.h>
#include <hip/hip_bf16.h>

#define B_ROWS 65536
#define D_IN   128
#define H_DIM  512
#define E_DIM  64
#define K_CODES 4096

typedef __bf16 bf16;
typedef __attribute__((ext_vector_type(8))) __bf16 bf16x8;
typedef __attribute__((ext_vector_type(4))) float f32x4;

// async global->LDS, 16 B per lane; LDS dest = wave-uniform base + lane*16
__device__ __forceinline__ void gld_lds16(const bf16* g, bf16* l)
{
    __builtin_amdgcn_global_load_lds((const __attribute__((address_space(1))) void*)g,
                                     (__attribute__((address_space(3))) void*)l,
                                     16, 0, 0);
}

// ---------------------------------------------------------------------------
// mfma_gemm2: proven BM=128/BK=32 single-barrier double-buffered loop,
// BN=128, TWO runtime problem descriptors per dispatch — the mini
// decoder-on-codebook GEMMs ride as extra grid blocks inside the big
// encoder GEMMs (R11-verified: 359.25 -> 333.7us).
// ---------------------------------------------------------------------------
struct GemmProb {
    const void* Ap; const bf16* WT;
    const float* scale; const float* shift;
    void* Cout;
    int N, K, NCB, nblk;   // nblk = (M/128)*NCB
};

template<bool CONV_A, bool RELU>
__global__ __launch_bounds__(256)
void mfma_gemm2(GemmProb pA, GemmProb pB)
{
    __shared__ bf16 As[2][128 * 32];
    __shared__ bf16 Bs[2][128 * 32];

    const int tid  = threadIdx.x;
    const int lane = tid & 63;
    const int wv   = tid >> 6;
    const int wm   = wv >> 1, wn = wv & 1;
    const int l16  = lane & 15, quad = lane >> 4;

    const bool second = (int)blockIdx.x >= pA.nblk;
    const GemmProb p = second ? pB : pA;
    const int bid = second ? (int)blockIdx.x - pA.nblk : (int)blockIdx.x;
    const int N = p.N, K = p.K, NCB = p.NCB;

    const int P = p.nblk / NCB;
    int panel, colb;
    if (NCB == 1 || (P & 7) != 0) {
        panel = bid % P;
        colb  = bid / P;
    } else {
        int xcd = bid & 7;
        int loc = bid >> 3;
        panel = xcd * (P >> 3) + loc / NCB;
        colb  = loc % NCB;
    }
    const size_t m0 = (size_t)panel * 128;
    const int  n0  = colb * 128;
    const int  csw = quad ^ ((l16 >> 1) & 3);
    const int  nk  = K >> 5;

    auto stage = [&](int s, int k0) {
        if constexpr (CONV_A) {
            const float* Af = (const float*)p.Ap;
#pragma unroll
            for (int ii = 0; ii < 2; ++ii) {
                int u = (wv + ii * 4) * 64 + lane;
                int r = u >> 2;
                int kg = (u & 3) ^ ((r >> 1) & 3);
                const float* src = Af + (m0 + r) * K + k0 + kg * 8;
                float4 v0 = *(const float4*)src;
                float4 v1 = *(const float4*)(src + 4);
                bf16 t[8] = {(bf16)v0.x, (bf16)v0.y, (bf16)v0.z, (bf16)v0.w,
                             (bf16)v1.x, (bf16)v1.y, (bf16)v1.z, (bf16)v1.w};
                *(bf16x8*)&As[s][u * 8] = *(bf16x8*)t;
            }
        } else {
            const bf16* Ab = (const bf16*)p.Ap;
#pragma unroll
            for (int ii = 0; ii < 2; ++ii) {
                int i = wv + ii * 4;
                int u = i * 64 + lane;
                int r = u >> 2;
                int kg = (u & 3) ^ ((r >> 1) & 3);
                gld_lds16(Ab + (m0 + r) * K + k0 + kg * 8, &As[s][i * 512]);
            }
        }
#pragma unroll
        for (int ii = 0; ii < 2; ++ii) {
            int i = wv + ii * 4;
            int u = i * 64 + lane;
            int r = u >> 2;
            int kg = (u & 3) ^ ((r >> 1) & 3);
            gld_lds16(p.WT + (size_t)(n0 + r) * K + k0 + kg * 8, &Bs[s][i * 512]);
        }
    };

    f32x4 acc[4][4] = {};
    stage(0, 0);
    for (int kt = 0; kt < nk; ++kt) {
        __syncthreads();
        if (kt + 1 < nk) stage((kt + 1) & 1, (kt + 1) * 32);
        const bf16* as = As[kt & 1];
        const bf16* bs = Bs[kt & 1];
        bf16x8 af[4], bfr[4];
#pragma unroll
        for (int i = 0; i < 4; ++i)
            af[i] = *(const bf16x8*)&as[(wm * 64 + i * 16 + l16) * 32 + csw * 8];
#pragma unroll
        for (int j = 0; j < 4; ++j)
            bfr[j] = *(const bf16x8*)&bs[(wn * 64 + j * 16 + l16) * 32 + csw * 8];
#pragma unroll
        for (int i = 0; i < 4; ++i)
#pragma unroll
            for (int j = 0; j < 4; ++j)
                acc[i][j] = __builtin_amdgcn_mfma_f32_16x16x32_bf16(af[i], bfr[j], acc[i][j], 0, 0, 0);
    }

#pragma unroll
    for (int i = 0; i < 4; ++i) {
#pragma unroll
        for (int j = 0; j < 4; ++j) {
            int col = n0 + wn * 64 + j * 16 + l16;
            float sc = p.scale ? p.scale[col] : 1.0f;
            float sh = p.shift[col];
#pragma unroll
            for (int r = 0; r < 4; ++r) {
                size_t row = m0 + wm * 64 + i * 16 + quad * 4 + r;
                float v = acc[i][j][r];
                v *= sc;
                v += sh;
                if (RELU) v = fmaxf(v, 0.0f);
                ((bf16*)p.Cout)[row * (size_t)N + col] = (bf16)v;
            }
        }
    }
}

// ---------------------------------------------------------------------------
// mfma_gemm4: dual-path G4 dispatch. Blocks [0,Penc): encoder G4
// (BN=64, K=256, FUSE_ZN epilogue: zb + zn = 0.5*z/||z||) — verbatim the
// mfma_gemm<64,1,false,false,false,false,true> instantiation. Blocks
// [Penc, Penc+32): mini-G4 (BN=128, K=512, OUT_F32 epilogue -> XRcb) —
// verbatim mfma_gemm<128,1,false,true,false,false,false>. Replaces the
// 32-block (12%-occupancy, ~12-15us) standalone mini-G4 dispatch.
// Branch is block-uniform; LDS sized for the max of both paths.
// ---------------------------------------------------------------------------
__global__ __launch_bounds__(256)
void mfma_gemm4(const bf16* __restrict__ Xb, const bf16* __restrict__ W4T,
                const float* __restrict__ b4, bf16* __restrict__ zb,
                bf16* __restrict__ zn, int Penc,
                const bf16* __restrict__ XR3, const bf16* __restrict__ D4T,
                const float* __restrict__ db4, float* __restrict__ XRcb)
{
    __shared__ bf16 As[2][128 * 32];
    __shared__ bf16 Bs[2][128 * 32];
    __shared__ float nrm2[256];

    const int tid  = threadIdx.x;
    const int lane = tid & 63;
    const int wv   = tid >> 6;
    const int wm   = wv >> 1, wn = wv & 1;
    const int l16  = lane & 15, quad = lane >> 4;
    const int csw  = quad ^ ((l16 >> 1) & 3);

    if ((int)blockIdx.x < Penc) {
        // ---- encoder G4: M=Penc*128, N=64, K=256, FUSE_ZN ----
        const size_t m0 = (size_t)blockIdx.x * 128;
        const int K = 256;

        auto stage = [&](int s, int k0) {
#pragma unroll
            for (int ii = 0; ii < 2; ++ii) {
                int i = wv + ii * 4;
                int u = i * 64 + lane;
                int r = u >> 2;
                int kg = (u & 3) ^ ((r >> 1) & 3);
                gld_lds16(Xb + (m0 + r) * K + k0 + kg * 8, &As[s][i * 512]);
            }
            {
                int i = wv;
                int u = i * 64 + lane;
                int r = u >> 2;
                int kg = (u & 3) ^ ((r >> 1) & 3);
                gld_lds16(W4T + (size_t)r * K + k0 + kg * 8, &Bs[s][i * 512]);
            }
        };

        f32x4 acc[4][2] = {};
        stage(0, 0);
        for (int kt = 0; kt < 8; ++kt) {
            __syncthreads();
            if (kt + 1 < 8) stage((kt + 1) & 1, (kt + 1) * 32);
            const bf16* as = As[kt & 1];
            const bf16* bs = Bs[kt & 1];
            bf16x8 af[4], bfr[2];
#pragma unroll
            for (int i = 0; i < 4; ++i)
                af[i] = *(const bf16x8*)&as[(wm * 64 + i * 16 + l16) * 32 + csw * 8];
#pragma unroll
            for (int j = 0; j < 2; ++j)
                bfr[j] = *(const bf16x8*)&bs[(wn * 32 + j * 16 + l16) * 32 + csw * 8];
#pragma unroll
            for (int i = 0; i < 4; ++i)
#pragma unroll
                for (int j = 0; j < 2; ++j)
                    acc[i][j] = __builtin_amdgcn_mfma_f32_16x16x32_bf16(af[i], bfr[j], acc[i][j], 0, 0, 0);
        }

        float vv[4][2][4];
        float pp[4][4];
#pragma unroll
        for (int i = 0; i < 4; ++i)
#pragma unroll
            for (int r = 0; r < 4; ++r) {
                float s = 0.f;
#pragma unroll
                for (int j = 0; j < 2; ++j) {
                    int col = wn * 32 + j * 16 + l16;
                    float v = acc[i][j][r] + b4[col];
                    vv[i][j][r] = v;
                    s = fmaf(v, v, s);
                }
                pp[i][r] = s;
            }
#pragma unroll
        for (int off = 1; off < 16; off <<= 1)
#pragma unroll
            for (int i = 0; i < 4; ++i)
#pragma unroll
                for (int r = 0; r < 4; ++r)
                    pp[i][r] += __shfl_xor(pp[i][r], off, 64);
        if (l16 == 0) {
#pragma unroll
            for (int i = 0; i < 4; ++i)
#pragma unroll
                for (int r = 0; r < 4; ++r)
                    nrm2[wn * 128 + wm * 64 + i * 16 + quad * 4 + r] = pp[i][r];
        }
        __syncthreads();
#pragma unroll
        for (int i = 0; i < 4; ++i)
#pragma unroll
            for (int r = 0; r < 4; ++r) {
                int rl = wm * 64 + i * 16 + quad * 4 + r;
                float s2 = nrm2[rl] + nrm2[128 + rl];
                float rn = 0.5f / fmaxf(sqrtf(s2), 1e-12f);
                size_t row = m0 + rl;
#pragma unroll
                for (int j = 0; j < 2; ++j) {
                    int col = wn * 32 + j * 16 + l16;
                    float v = vv[i][j][r];
                    zb[row * 64 + col] = (bf16)v;
                    zn[row * 64 + col] = (bf16)(v * rn);
                }
            }
    } else {
        // ---- mini G4: 4096x128x512, OUT_F32 -> XRcb ----
        const size_t m0 = (size_t)((int)blockIdx.x - Penc) * 128;
        const int K = 512;

        auto stage = [&](int s, int k0) {
#pragma unroll
            for (int ii = 0; ii < 2; ++ii) {
                int i = wv + ii * 4;
                int u = i * 64 + lane;
                int r = u >> 2;
                int kg = (u & 3) ^ ((r >> 1) & 3);
                gld_lds16(XR3 + (m0 + r) * K + k0 + kg * 8, &As[s][i * 512]);
            }
#pragma unroll
            for (int ii = 0; ii < 2; ++ii) {
                int i = wv + ii * 4;
                int u = i * 64 + lane;
                int r = u >> 2;
                int kg = (u & 3) ^ ((r >> 1) & 3);
                gld_lds16(D4T + (size_t)r * K + k0 + kg * 8, &Bs[s][i * 512]);
            }
        };

        f32x4 acc[4][4] = {};
        stage(0, 0);
        for (int kt = 0; kt < 16; ++kt) {
            __syncthreads();
            if (kt + 1 < 16) stage((kt + 1) & 1, (kt + 1) * 32);
            const bf16* as = As[kt & 1];
            const bf16* bs = Bs[kt & 1];
            bf16x8 af[4], bfr[4];
#pragma unroll
            for (int i = 0; i < 4; ++i)
                af[i] = *(const bf16x8*)&as[(wm * 64 + i * 16 + l16) * 32 + csw * 8];
#pragma unroll
            for (int j = 0; j < 4; ++j)
                bfr[j] = *(const bf16x8*)&bs[(wn * 64 + j * 16 + l16) * 32 + csw * 8];
#pragma unroll
            for (int i = 0; i < 4; ++i)
#pragma unroll
                for (int j = 0; j < 4; ++j)
                    acc[i][j] = __builtin_amdgcn_mfma_f32_16x16x32_bf16(af[i], bfr[j], acc[i][j], 0, 0, 0);
        }

#pragma unroll
        for (int i = 0; i < 4; ++i) {
#pragma unroll
            for (int j = 0; j < 4; ++j) {
                int col = wn * 64 + j * 16 + l16;
                float sh = db4[col];
#pragma unroll
                for (int r = 0; r < 4; ++r) {
                    size_t row = m0 + wm * 64 + i * 16 + quad * 4 + r;
                    XRcb[row * 128 + col] = acc[i][j][r] + sh;
                }
            }
        }
    }
}

// ---------------------------------------------------------------------------
// prep_transp: merged prep_misc + transp_all (both independent, input-only).
// blocks 0..1023 -> en; 1024..1039 -> zero counts; 1040 -> BN fold;
// 1041.. -> the 8 weight transposes.
// ---------------------------------------------------------------------------
struct TranspArgs { const float* s[8]; bf16* d[8]; };

__global__ __launch_bounds__(256)
void prep_transp(const float* __restrict__ emb, bf16* __restrict__ en,
                 unsigned int* __restrict__ counts,
                 const float* __restrict__ b1, const float* __restrict__ g1,
                 const float* __restrict__ be1, const float* __restrict__ rm1,
                 const float* __restrict__ rv1,
                 float* __restrict__ s1, float* __restrict__ sh1,
                 TranspArgs a)
{
    __shared__ float T[64][65];
    const int bid = blockIdx.x;
    const int tid = threadIdx.x;
    if (bid < 1024) {
        int lane = tid & 63;
        int row = bid * 4 + (tid >> 6);
        float v = emb[(size_t)row * E_DIM + lane];
        float ss = v * v;
#pragma unroll
        for (int o = 32; o > 0; o >>= 1) ss += __shfl_xor(ss, o, 64);
        float n = fmaxf(sqrtf(ss), 1e-12f);
        en[(size_t)row * E_DIM + lane] = (bf16)(v / n);
        return;
    }
    if (bid < 1040) {
        counts[(bid - 1024) * 256 + tid] = 0u;
        return;
    }
    if (bid == 1040) {
        for (int j = tid; j < H_DIM; j += 256) {
            float s = g1[j] * (1.0f / sqrtf(rv1[j] + 1e-5f));
            s1[j] = s;
            sh1[j] = (b1[j] - rm1[j]) * s + be1[j];
        }
        return;
    }
    // ---- transposes (bid-1041 in 0..231) ----
    constexpr int KS[8]  = {128, 512, 512, 256,  64, 256, 512, 512};
    constexpr int NS[8]  = {512, 512, 256,  64, 256, 512, 512, 128};
    constexpr int CUM[9] = {0, 16, 80, 112, 116, 120, 152, 216, 232};
    int tb = bid - 1041;
    int seg = 0;
#pragma unroll
    for (int s = 0; s < 8; ++s)
        if (tb >= CUM[s + 1]) seg = s + 1;
    const int bt = tb - CUM[seg];
    const int K = KS[seg], N = NS[seg];
    const int tiles_n = N / 64;
    const int k0 = (bt / tiles_n) * 64;
    const int n0 = (bt % tiles_n) * 64;
    const float* src = a.s[seg];
    bf16* dst = a.d[seg];

    const int rr = tid >> 6, cc = tid & 63;
#pragma unroll
    for (int pp = 0; pp < 16; ++pp) {
        int row = pp * 4 + rr;
        T[row][cc] = src[(size_t)(k0 + row) * N + n0 + cc];
    }
    __syncthreads();
#pragma unroll
    for (int pp = 0; pp < 16; ++pp) {
        int row = pp * 4 + rr;
        dst[(size_t)(n0 + row) * K + k0 + cc] = (bf16)T[cc][row];
    }
}

// ---------------------------------------------------------------------------
// vq_all: R6-verified structure (71.6us): 64 rows/block, 128-code LDS tiles,
// transposed wave->code mapping (wave owns 32-code slice, scans all 64 rows
// in registers; 4 ds_read_b128/wave/tile), packed-u8 LDS histogram,
// global count atomics at kernel end. 4 blocks/CU — the measured optimum
// (3grp=93, 4grp=71.6, 7grp/2x-barriers=99, 2grp=143).
// ---------------------------------------------------------------------------
__global__ __launch_bounds__(256, 4)
void vq_all(const bf16* __restrict__ zn, const bf16* __restrict__ zb,
            const bf16* __restrict__ en, const float* __restrict__ emb,
            const float* __restrict__ XR, float* __restrict__ xout,
            unsigned int* __restrict__ counts, float* __restrict__ psum, int gb0)
{
    __shared__ bf16 es[2][128 * 64];
    __shared__ unsigned hcnt[K_CODES / 4];   // 4 x u8 per word
    __shared__ int idxs[64];
    __shared__ float red[256];               // reused: u32 wave-best, then f32 reduce
    const int tid = threadIdx.x;
    const int lane = tid & 63;
    const int wv = tid >> 6;
    const int l16 = lane & 15, quad = lane >> 4;
    const long r0 = (long)blockIdx.x * 64;

    // A-fragments for ALL 64 rows of this block (rows are block-shared;
    // codes are wave-private). 8 x bf16x8 = 32 VGPRs.
    bf16x8 a0[4], a1[4];
#pragma unroll
    for (int rg = 0; rg < 4; ++rg) {
        long arow = r0 + rg * 16 + l16;
        a0[rg] = *(const bf16x8*)&zn[arow * E_DIM + quad * 8];
        a1[rg] = *(const bf16x8*)&zn[arow * E_DIM + 32 + quad * 8];
    }

    auto stage = [&](int s, int c0) {
#pragma unroll
        for (int ii = 0; ii < 4; ++ii) {
            int i = wv + ii * 4;
            int u = i * 64 + lane;
            int r = u >> 3;
            int kg = (u & 7) ^ (r & 7);
            gld_lds16(en + (size_t)(c0 + r) * E_DIM + kg * 8, &es[s][i * 512]);
        }
    };

    for (int j = tid; j < K_CODES / 4; j += 256) hcnt[j] = 0u;

    unsigned best[4][4];
#pragma unroll
    for (int rg = 0; rg < 4; ++rg)
#pragma unroll
        for (int r = 0; r < 4; ++r) best[rg][r] = 0u;
    const unsigned MASKHI = 0xFFFFF000u;

    stage(0, 0);
    for (int c0 = 0; c0 < K_CODES; c0 += 128) {
        __syncthreads();
        if (c0 + 128 < K_CODES) stage(((c0 >> 7) + 1) & 1, c0 + 128);
        const bf16* e = es[(c0 >> 7) & 1];
#pragma unroll
        for (int cg = 0; cg < 2; ++cg) {
            int srow = wv * 32 + cg * 16 + l16;      // code row within tile
            bf16x8 b0 = *(const bf16x8*)&e[srow * 64 + ((quad ^ (srow & 7)) * 8)];
            bf16x8 b1 = *(const bf16x8*)&e[srow * 64 + (((quad + 4) ^ (srow & 7)) * 8)];
            unsigned inv = (unsigned)(4095 - (c0 + srow));
#pragma unroll
            for (int rg = 0; rg < 4; ++rg) {
                f32x4 acc = {1.5f, 1.5f, 1.5f, 1.5f};
                acc = __builtin_amdgcn_mfma_f32_16x16x32_bf16(a0[rg], b0, acc, 0, 0, 0);
                acc = __builtin_amdgcn_mfma_f32_16x16x32_bf16(a1[rg], b1, acc, 0, 0, 0);
#pragma unroll
                for (int r = 0; r < 4; ++r) {
                    unsigned pk = (__float_as_uint(acc[r]) & MASKHI) | inv;
                    best[rg][r] = best[rg][r] > pk ? best[rg][r] : pk;
                }
            }
        }
    }
    // reduce across the 16 code-lanes (l16) for each of the 16 (rg,r) rows
#pragma unroll
    for (int off = 1; off < 16; off <<= 1) {
#pragma unroll
        for (int rg = 0; rg < 4; ++rg)
#pragma unroll
            for (int r = 0; r < 4; ++r) {
                unsigned o = (unsigned)__shfl_xor((int)best[rg][r], off, 64);
                best[rg][r] = best[rg][r] > o ? best[rg][r] : o;
            }
    }
    // per-wave per-row candidates -> LDS (red[] reused as u32 scratch)
    if (l16 == 0) {
        unsigned* wbest = (unsigned*)red;
#pragma unroll
        for (int rg = 0; rg < 4; ++rg)
#pragma unroll
            for (int r = 0; r < 4; ++r)
                wbest[wv * 64 + rg * 16 + quad * 4 + r] = best[rg][r];
    }
    __syncthreads();
    if (tid < 64) {
        const unsigned* wbest = (const unsigned*)red;
        unsigned m0 = wbest[tid],       m1 = wbest[64 + tid];
        unsigned m2 = wbest[128 + tid], m3 = wbest[192 + tid];
        unsigned m = m0 > m1 ? m0 : m1;
        unsigned n = m2 > m3 ? m2 : m3;
        m = m > n ? m : n;
        int b = 4095 - (int)(m & 0xFFFu);
        idxs[tid] = b;
        atomicAdd(&hcnt[b >> 2], 1u << ((b & 3) * 8));
    }
    __syncthreads();

    // post phase: wave wv handles rows wv, wv+4, ...
    float local = 0.f;
#pragma unroll 4
    for (int i = 0; i < 16; ++i) {
        int rl = wv + 4 * i;
        long row = r0 + rl;
        int id = idxs[rl] & (K_CODES - 1);
        float qv = emb[(size_t)id * E_DIM + lane];
        float zv = (float)zb[row * E_DIM + lane];
        float d = qv - zv;
        local = fmaf(d, d, local);
        float2 xv = *(const float2*)(XR + (size_t)id * D_IN + 2 * lane);
        float* dst = xout + (size_t)row * D_IN + 2 * lane;
        dst[0] = xv.x;
        dst[1] = xv.y;
    }
    red[tid] = local;
    __syncthreads();
    for (int s = 128; s > 0; s >>= 1) {
        if (tid < s) red[tid] += red[tid + s];
        __syncthreads();
    }
    if (tid == 0) psum[gb0 + blockIdx.x] = red[0];
    for (int j = tid; j < K_CODES / 4; j += 256) {
        unsigned w = hcnt[j];
        if (w) {
#pragma unroll
            for (int k = 0; k < 4; ++k) {
                unsigned c = (w >> (k * 8)) & 255u;
                if (c) atomicAdd(&counts[j * 4 + k], c);
            }
        }
    }
}

// ---------------------------------------------------------------------------
__global__ __launch_bounds__(1024)
void finalize_k(const unsigned int* __restrict__ counts, const float* __restrict__ psum,
                float* __restrict__ out_loss, float* __restrict__ out_perp)
{
    __shared__ float red[1024];
    const int tid = threadIdx.x;
    red[tid] = psum[tid];
    __syncthreads();
    for (int s = 512; s > 0; s >>= 1) {
        if (tid < s) red[tid] += red[tid + s];
        __syncthreads();
    }
    if (tid == 0)
        out_loss[0] = 1.02f * (red[0] * (1.0f / ((float)B_ROWS * (float)E_DIM)));
    __syncthreads();
    float e = 0.f;
    for (int j = tid; j < K_CODES; j += 1024) {
        float pr = (float)counts[j] * (1.0f / (float)B_ROWS);
        e += pr * logf(pr + 1e-10f);
    }
    red[tid] = e;
    __syncthreads();
    for (int s = 512; s > 0; s >>= 1) {
        if (tid < s) red[tid] += red[tid + s];
        __syncthreads();
    }
    if (tid == 0) out_perp[0] = expf(-red[0]);
}

// ---------------------------------------------------------------------------
extern "C" void kernel_launch(void* const* d_in, const int* in_sizes, int n_in,
                              void* d_out, int out_size, void* d_ws, size_t ws_size,
                              hipStream_t stream)
{
    const float* x   = (const float*)d_in[0];
    const float* W1  = (const float*)d_in[1];
    const float* b1  = (const float*)d_in[2];
    const float* g1  = (const float*)d_in[3];
    const float* be1 = (const float*)d_in[4];
    const float* rm1 = (const float*)d_in[5];
    const float* rv1 = (const float*)d_in[6];
    const float* W2  = (const float*)d_in[7];
    const float* b2  = (const float*)d_in[8];
    const float* W3  = (const float*)d_in[9];
    const float* b3  = (const float*)d_in[10];
    const float* W4  = (const float*)d_in[11];
    const float* b4  = (const float*)d_in[12];
    const float* emb = (const float*)d_in[13];
    const float* Dw1 = (const float*)d_in[14];
    const float* db1 = (const float*)d_in[15];
    const float* Dw2 = (const float*)d_in[16];
    const float* db2 = (const float*)d_in[17];
    const float* Dw3 = (const float*)d_in[18];
    const float* db3 = (const float*)d_in[19];
    const float* Dw4 = (const float*)d_in[20];
    const float* db4 = (const float*)d_in[21];
    float* out = (float*)d_out;
    (void)in_sizes; (void)n_in;

    // ---- workspace carve-up (256B-aligned) ----
    char* p = (char*)d_ws;
    size_t off = 0;
    auto alloc = [&](size_t bytes) -> char* {
        char* r = p + off;
        off = (off + bytes + 255) & ~(size_t)255;
        return r;
    };
    bf16* en  = (bf16*)alloc((size_t)K_CODES * E_DIM * 2);
    bf16* W1T = (bf16*)alloc((size_t)D_IN * H_DIM * 2);
    bf16* W2T = (bf16*)alloc((size_t)H_DIM * H_DIM * 2);
    bf16* W3T = (bf16*)alloc((size_t)H_DIM * (H_DIM / 2) * 2);
    bf16* W4T = (bf16*)alloc((size_t)(H_DIM / 2) * E_DIM * 2);
    bf16* D1T = (bf16*)alloc((size_t)E_DIM * (H_DIM / 2) * 2);
    bf16* D2T = (bf16*)alloc((size_t)(H_DIM / 2) * H_DIM * 2);
    bf16* D3T = (bf16*)alloc((size_t)H_DIM * H_DIM * 2);
    bf16* D4T = (bf16*)alloc((size_t)H_DIM * D_IN * 2);
    float* s1  = (float*)alloc(H_DIM * 4);
    float* sh1 = (float*)alloc(H_DIM * 4);
    unsigned int* counts = (unsigned int*)alloc(K_CODES * 4);
    float* psum = (float*)alloc((B_ROWS / 64) * 4);
    // mini decoder-on-codebook buffers
    bf16*  XR1  = (bf16*)alloc((size_t)K_CODES * (H_DIM / 2) * 2);  // 4096x256
    bf16*  XR2  = (bf16*)alloc((size_t)K_CODES * H_DIM * 2);        // 4096x512
    bf16*  XR3  = (bf16*)alloc((size_t)K_CODES * H_DIM * 2);        // 4096x512
    float* XRcb = (float*)alloc((size_t)K_CODES * D_IN * 4);        // 4096x128 f32
    size_t fixed_bytes = off;

    // per-chunk: Xb CH*1024 + Yb CH*1024 + zb CH*128 + zn CH*128
    int CH = 128;
    for (int c = B_ROWS; c >= 128; c >>= 1) {
        if (fixed_bytes + (size_t)c * 2304 + 4096 <= ws_size) { CH = c; break; }
    }
    bf16* Xb = (bf16*)alloc((size_t)CH * H_DIM * 2);
    bf16* Yb = (bf16*)alloc((size_t)CH * H_DIM * 2);
    bf16* zb = (bf16*)alloc((size_t)CH * E_DIM * 2);
    bf16* zn = (bf16*)alloc((size_t)CH * E_DIM * 2);

    // ---- prep + transposes, one dispatch ----
    TranspArgs ta;
    ta.s[0] = W1;  ta.d[0] = W1T;
    ta.s[1] = W2;  ta.d[1] = W2T;
    ta.s[2] = W3;  ta.d[2] = W3T;
    ta.s[3] = W4;  ta.d[3] = W4T;
    ta.s[4] = Dw1; ta.d[4] = D1T;
    ta.s[5] = Dw2; ta.d[5] = D2T;
    ta.s[6] = Dw3; ta.d[6] = D3T;
    ta.s[7] = Dw4; ta.d[7] = D4T;
    prep_transp<<<1041 + 232, 256, 0, stream>>>(emb, en, counts, b1, g1, be1, rm1, rv1, s1, sh1, ta);

    dim3 blk(256);
    const GemmProb NONE = {nullptr, nullptr, nullptr, nullptr, nullptr, 0, 0, 1, 0};

    for (int c0 = 0; c0 < B_ROWS; c0 += CH) {
        const int M = CH;
        const int P = M / 128;
        const bool z = (c0 == 0);   // zip the one-time mini decoder chain
                                    // (XRcb[c]=dec(emb[c])) into chunk 0's
                                    // encoder dispatches as extra blocks

        GemmProb e1 = {x + (size_t)c0 * D_IN, W1T, s1, sh1, Xb, 512, 128, 4, P * 4};
        GemmProb m1 = {emb, D1T, nullptr, db1, XR1, 256, 64, 2, 64};
        mfma_gemm2<true , true><<<e1.nblk + (z ? m1.nblk : 0), blk, 0, stream>>>(e1, z ? m1 : NONE);

        GemmProb e2 = {Xb, W2T, nullptr, b2, Yb, 512, 512, 4, P * 4};
        GemmProb m2 = {XR1, D2T, nullptr, db2, XR2, 512, 256, 4, 128};
        mfma_gemm2<false, true><<<e2.nblk + (z ? m2.nblk : 0), blk, 0, stream>>>(e2, z ? m2 : NONE);

        GemmProb e3 = {Yb, W3T, nullptr, b3, Xb, 256, 512, 2, P * 2};
        GemmProb m3 = {XR2, D3T, nullptr, db3, XR3, 512, 512, 4, 128};
        mfma_gemm2<false, true><<<e3.nblk + (z ? m3.nblk : 0), blk, 0, stream>>>(e3, z ? m3 : NONE);

        // G4: encoder FUSE_ZN (P blocks) + zipped mini-G4 (32 blocks, once)
        mfma_gemm4<<<P + (z ? 32 : 0), blk, 0, stream>>>(Xb, W4T, b4, zb, zn, P,
                                                         XR3, D4T, db4, XRcb);

        // VQ: argmin + histogram + sumsq + x_recon scatter, one kernel
        vq_all<<<M / 64, 256, 0, stream>>>(zn, zb, en, emb, XRcb,
                                           out + 1 + (size_t)c0 * D_IN,
                                           counts, psum, c0 / 64);
    }

    finalize_k<<<1, 1024, 0, stream>>>(counts, psum, out, out + (out_size - 1));
}

// Round 13
// 332.616 us; speedup vs baseline: 1.5361x; 1.0012x over previous
//
#include <hip/hip_runtime.h>
#include <hip/hip_bf16.h>

#define B_ROWS 65536
#define D_IN   128
#define H_DIM  512
#define E_DIM  64
#define K_CODES 4096

typedef __bf16 bf16;
typedef __attribute__((ext_vector_type(8))) __bf16 bf16x8;
typedef __attribute__((ext_vector_type(4))) float f32x4;

// async global->LDS, 16 B per lane; LDS dest = wave-uniform base + lane*16
__device__ __forceinline__ void gld_lds16(const bf16* g, bf16* l)
{
    __builtin_amdgcn_global_load_lds((const __attribute__((address_space(1))) void*)g,
                                     (__attribute__((address_space(3))) void*)l,
                                     16, 0, 0);
}

// ---------------------------------------------------------------------------
// mfma_gemm2: proven BM=128/BK=32 single-barrier double-buffered loop,
// BN=128, TWO runtime problem descriptors per dispatch (R11: 359->333.7us).
// __launch_bounds__(256,4): cap VGPR at 128 so each CU holds 4 independent
// barrier groups — the session-verified lever for this 2-barrier K-loop
// (vq data: 2grp=143us, 3grp=93, 4grp=71.6 on the same structure).
// ---------------------------------------------------------------------------
struct GemmProb {
    const void* Ap; const bf16* WT;
    const float* scale; const float* shift;
    void* Cout;
    int N, K, NCB, nblk;   // nblk = (M/128)*NCB
};

template<bool CONV_A, bool RELU>
__global__ __launch_bounds__(256, 4)
void mfma_gemm2(GemmProb pA, GemmProb pB)
{
    __shared__ bf16 As[2][128 * 32];
    __shared__ bf16 Bs[2][128 * 32];

    const int tid  = threadIdx.x;
    const int lane = tid & 63;
    const int wv   = tid >> 6;
    const int wm   = wv >> 1, wn = wv & 1;
    const int l16  = lane & 15, quad = lane >> 4;

    const bool second = (int)blockIdx.x >= pA.nblk;
    const GemmProb p = second ? pB : pA;
    const int bid = second ? (int)blockIdx.x - pA.nblk : (int)blockIdx.x;
    const int N = p.N, K = p.K, NCB = p.NCB;

    const int P = p.nblk / NCB;
    int panel, colb;
    if (NCB == 1 || (P & 7) != 0) {
        panel = bid % P;
        colb  = bid / P;
    } else {
        int xcd = bid & 7;
        int loc = bid >> 3;
        panel = xcd * (P >> 3) + loc / NCB;
        colb  = loc % NCB;
    }
    const size_t m0 = (size_t)panel * 128;
    const int  n0  = colb * 128;
    const int  csw = quad ^ ((l16 >> 1) & 3);
    const int  nk  = K >> 5;

    auto stage = [&](int s, int k0) {
        if constexpr (CONV_A) {
            const float* Af = (const float*)p.Ap;
#pragma unroll
            for (int ii = 0; ii < 2; ++ii) {
                int u = (wv + ii * 4) * 64 + lane;
                int r = u >> 2;
                int kg = (u & 3) ^ ((r >> 1) & 3);
                const float* src = Af + (m0 + r) * K + k0 + kg * 8;
                float4 v0 = *(const float4*)src;
                float4 v1 = *(const float4*)(src + 4);
                bf16 t[8] = {(bf16)v0.x, (bf16)v0.y, (bf16)v0.z, (bf16)v0.w,
                             (bf16)v1.x, (bf16)v1.y, (bf16)v1.z, (bf16)v1.w};
                *(bf16x8*)&As[s][u * 8] = *(bf16x8*)t;
            }
        } else {
            const bf16* Ab = (const bf16*)p.Ap;
#pragma unroll
            for (int ii = 0; ii < 2; ++ii) {
                int i = wv + ii * 4;
                int u = i * 64 + lane;
                int r = u >> 2;
                int kg = (u & 3) ^ ((r >> 1) & 3);
                gld_lds16(Ab + (m0 + r) * K + k0 + kg * 8, &As[s][i * 512]);
            }
        }
#pragma unroll
        for (int ii = 0; ii < 2; ++ii) {
            int i = wv + ii * 4;
            int u = i * 64 + lane;
            int r = u >> 2;
            int kg = (u & 3) ^ ((r >> 1) & 3);
            gld_lds16(p.WT + (size_t)(n0 + r) * K + k0 + kg * 8, &Bs[s][i * 512]);
        }
    };

    f32x4 acc[4][4] = {};
    stage(0, 0);
    for (int kt = 0; kt < nk; ++kt) {
        __syncthreads();
        if (kt + 1 < nk) stage((kt + 1) & 1, (kt + 1) * 32);
        const bf16* as = As[kt & 1];
        const bf16* bs = Bs[kt & 1];
        bf16x8 af[4], bfr[4];
#pragma unroll
        for (int i = 0; i < 4; ++i)
            af[i] = *(const bf16x8*)&as[(wm * 64 + i * 16 + l16) * 32 + csw * 8];
#pragma unroll
        for (int j = 0; j < 4; ++j)
            bfr[j] = *(const bf16x8*)&bs[(wn * 64 + j * 16 + l16) * 32 + csw * 8];
#pragma unroll
        for (int i = 0; i < 4; ++i)
#pragma unroll
            for (int j = 0; j < 4; ++j)
                acc[i][j] = __builtin_amdgcn_mfma_f32_16x16x32_bf16(af[i], bfr[j], acc[i][j], 0, 0, 0);
    }

#pragma unroll
    for (int i = 0; i < 4; ++i) {
#pragma unroll
        for (int j = 0; j < 4; ++j) {
            int col = n0 + wn * 64 + j * 16 + l16;
            float sc = p.scale ? p.scale[col] : 1.0f;
            float sh = p.shift[col];
#pragma unroll
            for (int r = 0; r < 4; ++r) {
                size_t row = m0 + wm * 64 + i * 16 + quad * 4 + r;
                float v = acc[i][j][r];
                v *= sc;
                v += sh;
                if (RELU) v = fmaxf(v, 0.0f);
                ((bf16*)p.Cout)[row * (size_t)N + col] = (bf16)v;
            }
        }
    }
}

// ---------------------------------------------------------------------------
// mfma_gemm4: dual-path G4 dispatch (R12). Blocks [0,Penc): encoder G4
// (BN=64, K=256, FUSE_ZN). Blocks [Penc,Penc+32): mini-G4 (BN=128, K=512,
// OUT_F32 -> XRcb). __launch_bounds__(256,4): same 4-group residency cap.
// ---------------------------------------------------------------------------
__global__ __launch_bounds__(256, 4)
void mfma_gemm4(const bf16* __restrict__ Xb, const bf16* __restrict__ W4T,
                const float* __restrict__ b4, bf16* __restrict__ zb,
                bf16* __restrict__ zn, int Penc,
                const bf16* __restrict__ XR3, const bf16* __restrict__ D4T,
                const float* __restrict__ db4, float* __restrict__ XRcb)
{
    __shared__ bf16 As[2][128 * 32];
    __shared__ bf16 Bs[2][128 * 32];
    __shared__ float nrm2[256];

    const int tid  = threadIdx.x;
    const int lane = tid & 63;
    const int wv   = tid >> 6;
    const int wm   = wv >> 1, wn = wv & 1;
    const int l16  = lane & 15, quad = lane >> 4;
    const int csw  = quad ^ ((l16 >> 1) & 3);

    if ((int)blockIdx.x < Penc) {
        // ---- encoder G4: M=Penc*128, N=64, K=256, FUSE_ZN ----
        const size_t m0 = (size_t)blockIdx.x * 128;
        const int K = 256;

        auto stage = [&](int s, int k0) {
#pragma unroll
            for (int ii = 0; ii < 2; ++ii) {
                int i = wv + ii * 4;
                int u = i * 64 + lane;
                int r = u >> 2;
                int kg = (u & 3) ^ ((r >> 1) & 3);
                gld_lds16(Xb + (m0 + r) * K + k0 + kg * 8, &As[s][i * 512]);
            }
            {
                int i = wv;
                int u = i * 64 + lane;
                int r = u >> 2;
                int kg = (u & 3) ^ ((r >> 1) & 3);
                gld_lds16(W4T + (size_t)r * K + k0 + kg * 8, &Bs[s][i * 512]);
            }
        };

        f32x4 acc[4][2] = {};
        stage(0, 0);
        for (int kt = 0; kt < 8; ++kt) {
            __syncthreads();
            if (kt + 1 < 8) stage((kt + 1) & 1, (kt + 1) * 32);
            const bf16* as = As[kt & 1];
            const bf16* bs = Bs[kt & 1];
            bf16x8 af[4], bfr[2];
#pragma unroll
            for (int i = 0; i < 4; ++i)
                af[i] = *(const bf16x8*)&as[(wm * 64 + i * 16 + l16) * 32 + csw * 8];
#pragma unroll
            for (int j = 0; j < 2; ++j)
                bfr[j] = *(const bf16x8*)&bs[(wn * 32 + j * 16 + l16) * 32 + csw * 8];
#pragma unroll
            for (int i = 0; i < 4; ++i)
#pragma unroll
                for (int j = 0; j < 2; ++j)
                    acc[i][j] = __builtin_amdgcn_mfma_f32_16x16x32_bf16(af[i], bfr[j], acc[i][j], 0, 0, 0);
        }

        float vv[4][2][4];
        float pp[4][4];
#pragma unroll
        for (int i = 0; i < 4; ++i)
#pragma unroll
            for (int r = 0; r < 4; ++r) {
                float s = 0.f;
#pragma unroll
                for (int j = 0; j < 2; ++j) {
                    int col = wn * 32 + j * 16 + l16;
                    float v = acc[i][j][r] + b4[col];
                    vv[i][j][r] = v;
                    s = fmaf(v, v, s);
                }
                pp[i][r] = s;
            }
#pragma unroll
        for (int off = 1; off < 16; off <<= 1)
#pragma unroll
            for (int i = 0; i < 4; ++i)
#pragma unroll
                for (int r = 0; r < 4; ++r)
                    pp[i][r] += __shfl_xor(pp[i][r], off, 64);
        if (l16 == 0) {
#pragma unroll
            for (int i = 0; i < 4; ++i)
#pragma unroll
                for (int r = 0; r < 4; ++r)
                    nrm2[wn * 128 + wm * 64 + i * 16 + quad * 4 + r] = pp[i][r];
        }
        __syncthreads();
#pragma unroll
        for (int i = 0; i < 4; ++i)
#pragma unroll
            for (int r = 0; r < 4; ++r) {
                int rl = wm * 64 + i * 16 + quad * 4 + r;
                float s2 = nrm2[rl] + nrm2[128 + rl];
                float rn = 0.5f / fmaxf(sqrtf(s2), 1e-12f);
                size_t row = m0 + rl;
#pragma unroll
                for (int j = 0; j < 2; ++j) {
                    int col = wn * 32 + j * 16 + l16;
                    float v = vv[i][j][r];
                    zb[row * 64 + col] = (bf16)v;
                    zn[row * 64 + col] = (bf16)(v * rn);
                }
            }
    } else {
        // ---- mini G4: 4096x128x512, OUT_F32 -> XRcb ----
        const size_t m0 = (size_t)((int)blockIdx.x - Penc) * 128;
        const int K = 512;

        auto stage = [&](int s, int k0) {
#pragma unroll
            for (int ii = 0; ii < 2; ++ii) {
                int i = wv + ii * 4;
                int u = i * 64 + lane;
                int r = u >> 2;
                int kg = (u & 3) ^ ((r >> 1) & 3);
                gld_lds16(XR3 + (m0 + r) * K + k0 + kg * 8, &As[s][i * 512]);
            }
#pragma unroll
            for (int ii = 0; ii < 2; ++ii) {
                int i = wv + ii * 4;
                int u = i * 64 + lane;
                int r = u >> 2;
                int kg = (u & 3) ^ ((r >> 1) & 3);
                gld_lds16(D4T + (size_t)r * K + k0 + kg * 8, &Bs[s][i * 512]);
            }
        };

        f32x4 acc[4][4] = {};
        stage(0, 0);
        for (int kt = 0; kt < 16; ++kt) {
            __syncthreads();
            if (kt + 1 < 16) stage((kt + 1) & 1, (kt + 1) * 32);
            const bf16* as = As[kt & 1];
            const bf16* bs = Bs[kt & 1];
            bf16x8 af[4], bfr[4];
#pragma unroll
            for (int i = 0; i < 4; ++i)
                af[i] = *(const bf16x8*)&as[(wm * 64 + i * 16 + l16) * 32 + csw * 8];
#pragma unroll
            for (int j = 0; j < 4; ++j)
                bfr[j] = *(const bf16x8*)&bs[(wn * 64 + j * 16 + l16) * 32 + csw * 8];
#pragma unroll
            for (int i = 0; i < 4; ++i)
#pragma unroll
                for (int j = 0; j < 4; ++j)
                    acc[i][j] = __builtin_amdgcn_mfma_f32_16x16x32_bf16(af[i], bfr[j], acc[i][j], 0, 0, 0);
        }

#pragma unroll
        for (int i = 0; i < 4; ++i) {
#pragma unroll
            for (int j = 0; j < 4; ++j) {
                int col = wn * 64 + j * 16 + l16;
                float sh = db4[col];
#pragma unroll
                for (int r = 0; r < 4; ++r) {
                    size_t row = m0 + wm * 64 + i * 16 + quad * 4 + r;
                    XRcb[row * 128 + col] = acc[i][j][r] + sh;
                }
            }
        }
    }
}

// ---------------------------------------------------------------------------
// prep_transp: merged prep_misc + transp_all (both independent, input-only).
// blocks 0..1023 -> en; 1024..1039 -> zero counts; 1040 -> BN fold;
// 1041.. -> the 8 weight transposes.
// ---------------------------------------------------------------------------
struct TranspArgs { const float* s[8]; bf16* d[8]; };

__global__ __launch_bounds__(256)
void prep_transp(const float* __restrict__ emb, bf16* __restrict__ en,
                 unsigned int* __restrict__ counts,
                 const float* __restrict__ b1, const float* __restrict__ g1,
                 const float* __restrict__ be1, const float* __restrict__ rm1,
                 const float* __restrict__ rv1,
                 float* __restrict__ s1, float* __restrict__ sh1,
                 TranspArgs a)
{
    __shared__ float T[64][65];
    const int bid = blockIdx.x;
    const int tid = threadIdx.x;
    if (bid < 1024) {
        int lane = tid & 63;
        int row = bid * 4 + (tid >> 6);
        float v = emb[(size_t)row * E_DIM + lane];
        float ss = v * v;
#pragma unroll
        for (int o = 32; o > 0; o >>= 1) ss += __shfl_xor(ss, o, 64);
        float n = fmaxf(sqrtf(ss), 1e-12f);
        en[(size_t)row * E_DIM + lane] = (bf16)(v / n);
        return;
    }
    if (bid < 1040) {
        counts[(bid - 1024) * 256 + tid] = 0u;
        return;
    }
    if (bid == 1040) {
        for (int j = tid; j < H_DIM; j += 256) {
            float s = g1[j] * (1.0f / sqrtf(rv1[j] + 1e-5f));
            s1[j] = s;
            sh1[j] = (b1[j] - rm1[j]) * s + be1[j];
        }
        return;
    }
    // ---- transposes (bid-1041 in 0..231) ----
    constexpr int KS[8]  = {128, 512, 512, 256,  64, 256, 512, 512};
    constexpr int NS[8]  = {512, 512, 256,  64, 256, 512, 512, 128};
    constexpr int CUM[9] = {0, 16, 80, 112, 116, 120, 152, 216, 232};
    int tb = bid - 1041;
    int seg = 0;
#pragma unroll
    for (int s = 0; s < 8; ++s)
        if (tb >= CUM[s + 1]) seg = s + 1;
    const int bt = tb - CUM[seg];
    const int K = KS[seg], N = NS[seg];
    const int tiles_n = N / 64;
    const int k0 = (bt / tiles_n) * 64;
    const int n0 = (bt % tiles_n) * 64;
    const float* src = a.s[seg];
    bf16* dst = a.d[seg];

    const int rr = tid >> 6, cc = tid & 63;
#pragma unroll
    for (int pp = 0; pp < 16; ++pp) {
        int row = pp * 4 + rr;
        T[row][cc] = src[(size_t)(k0 + row) * N + n0 + cc];
    }
    __syncthreads();
#pragma unroll
    for (int pp = 0; pp < 16; ++pp) {
        int row = pp * 4 + rr;
        dst[(size_t)(n0 + row) * K + k0 + cc] = (bf16)T[cc][row];
    }
}

// ---------------------------------------------------------------------------
// vq_all: R6-verified structure (71.6us): 64 rows/block, 128-code LDS tiles,
// transposed wave->code mapping (wave owns 32-code slice, scans all 64 rows
// in registers; 4 ds_read_b128/wave/tile), packed-u8 LDS histogram,
// global count atomics at kernel end. 4 blocks/CU — the measured optimum
// (3grp=93, 4grp=71.6, 7grp/2x-barriers=99, 2grp=143).
// ---------------------------------------------------------------------------
__global__ __launch_bounds__(256, 4)
void vq_all(const bf16* __restrict__ zn, const bf16* __restrict__ zb,
            const bf16* __restrict__ en, const float* __restrict__ emb,
            const float* __restrict__ XR, float* __restrict__ xout,
            unsigned int* __restrict__ counts, float* __restrict__ psum, int gb0)
{
    __shared__ bf16 es[2][128 * 64];
    __shared__ unsigned hcnt[K_CODES / 4];   // 4 x u8 per word
    __shared__ int idxs[64];
    __shared__ float red[256];               // reused: u32 wave-best, then f32 reduce
    const int tid = threadIdx.x;
    const int lane = tid & 63;
    const int wv = tid >> 6;
    const int l16 = lane & 15, quad = lane >> 4;
    const long r0 = (long)blockIdx.x * 64;

    // A-fragments for ALL 64 rows of this block (rows are block-shared;
    // codes are wave-private). 8 x bf16x8 = 32 VGPRs.
    bf16x8 a0[4], a1[4];
#pragma unroll
    for (int rg = 0; rg < 4; ++rg) {
        long arow = r0 + rg * 16 + l16;
        a0[rg] = *(const bf16x8*)&zn[arow * E_DIM + quad * 8];
        a1[rg] = *(const bf16x8*)&zn[arow * E_DIM + 32 + quad * 8];
    }

    auto stage = [&](int s, int c0) {
#pragma unroll
        for (int ii = 0; ii < 4; ++ii) {
            int i = wv + ii * 4;
            int u = i * 64 + lane;
            int r = u >> 3;
            int kg = (u & 7) ^ (r & 7);
            gld_lds16(en + (size_t)(c0 + r) * E_DIM + kg * 8, &es[s][i * 512]);
        }
    };

    for (int j = tid; j < K_CODES / 4; j += 256) hcnt[j] = 0u;

    unsigned best[4][4];
#pragma unroll
    for (int rg = 0; rg < 4; ++rg)
#pragma unroll
        for (int r = 0; r < 4; ++r) best[rg][r] = 0u;
    const unsigned MASKHI = 0xFFFFF000u;

    stage(0, 0);
    for (int c0 = 0; c0 < K_CODES; c0 += 128) {
        __syncthreads();
        if (c0 + 128 < K_CODES) stage(((c0 >> 7) + 1) & 1, c0 + 128);
        const bf16* e = es[(c0 >> 7) & 1];
#pragma unroll
        for (int cg = 0; cg < 2; ++cg) {
            int srow = wv * 32 + cg * 16 + l16;      // code row within tile
            bf16x8 b0 = *(const bf16x8*)&e[srow * 64 + ((quad ^ (srow & 7)) * 8)];
            bf16x8 b1 = *(const bf16x8*)&e[srow * 64 + (((quad + 4) ^ (srow & 7)) * 8)];
            unsigned inv = (unsigned)(4095 - (c0 + srow));
#pragma unroll
            for (int rg = 0; rg < 4; ++rg) {
                f32x4 acc = {1.5f, 1.5f, 1.5f, 1.5f};
                acc = __builtin_amdgcn_mfma_f32_16x16x32_bf16(a0[rg], b0, acc, 0, 0, 0);
                acc = __builtin_amdgcn_mfma_f32_16x16x32_bf16(a1[rg], b1, acc, 0, 0, 0);
#pragma unroll
                for (int r = 0; r < 4; ++r) {
                    unsigned pk = (__float_as_uint(acc[r]) & MASKHI) | inv;
                    best[rg][r] = best[rg][r] > pk ? best[rg][r] : pk;
                }
            }
        }
    }
    // reduce across the 16 code-lanes (l16) for each of the 16 (rg,r) rows
#pragma unroll
    for (int off = 1; off < 16; off <<= 1) {
#pragma unroll
        for (int rg = 0; rg < 4; ++rg)
#pragma unroll
            for (int r = 0; r < 4; ++r) {
                unsigned o = (unsigned)__shfl_xor((int)best[rg][r], off, 64);
                best[rg][r] = best[rg][r] > o ? best[rg][r] : o;
            }
    }
    // per-wave per-row candidates -> LDS (red[] reused as u32 scratch)
    if (l16 == 0) {
        unsigned* wbest = (unsigned*)red;
#pragma unroll
        for (int rg = 0; rg < 4; ++rg)
#pragma unroll
            for (int r = 0; r < 4; ++r)
                wbest[wv * 64 + rg * 16 + quad * 4 + r] = best[rg][r];
    }
    __syncthreads();
    if (tid < 64) {
        const unsigned* wbest = (const unsigned*)red;
        unsigned m0 = wbest[tid],       m1 = wbest[64 + tid];
        unsigned m2 = wbest[128 + tid], m3 = wbest[192 + tid];
        unsigned m = m0 > m1 ? m0 : m1;
        unsigned n = m2 > m3 ? m2 : m3;
        m = m > n ? m : n;
        int b = 4095 - (int)(m & 0xFFFu);
        idxs[tid] = b;
        atomicAdd(&hcnt[b >> 2], 1u << ((b & 3) * 8));
    }
    __syncthreads();

    // post phase: wave wv handles rows wv, wv+4, ...
    float local = 0.f;
#pragma unroll 4
    for (int i = 0; i < 16; ++i) {
        int rl = wv + 4 * i;
        long row = r0 + rl;
        int id = idxs[rl] & (K_CODES - 1);
        float qv = emb[(size_t)id * E_DIM + lane];
        float zv = (float)zb[row * E_DIM + lane];
        float d = qv - zv;
        local = fmaf(d, d, local);
        float2 xv = *(const float2*)(XR + (size_t)id * D_IN + 2 * lane);
        float* dst = xout + (size_t)row * D_IN + 2 * lane;
        dst[0] = xv.x;
        dst[1] = xv.y;
    }
    red[tid] = local;
    __syncthreads();
    for (int s = 128; s > 0; s >>= 1) {
        if (tid < s) red[tid] += red[tid + s];
        __syncthreads();
    }
    if (tid == 0) psum[gb0 + blockIdx.x] = red[0];
    for (int j = tid; j < K_CODES / 4; j += 256) {
        unsigned w = hcnt[j];
        if (w) {
#pragma unroll
            for (int k = 0; k < 4; ++k) {
                unsigned c = (w >> (k * 8)) & 255u;
                if (c) atomicAdd(&counts[j * 4 + k], c);
            }
        }
    }
}

// ---------------------------------------------------------------------------
__global__ __launch_bounds__(1024)
void finalize_k(const unsigned int* __restrict__ counts, const float* __restrict__ psum,
                float* __restrict__ out_loss, float* __restrict__ out_perp)
{
    __shared__ float red[1024];
    const int tid = threadIdx.x;
    red[tid] = psum[tid];
    __syncthreads();
    for (int s = 512; s > 0; s >>= 1) {
        if (tid < s) red[tid] += red[tid + s];
        __syncthreads();
    }
    if (tid == 0)
        out_loss[0] = 1.02f * (red[0] * (1.0f / ((float)B_ROWS * (float)E_DIM)));
    __syncthreads();
    float e = 0.f;
    for (int j = tid; j < K_CODES; j += 1024) {
        float pr = (float)counts[j] * (1.0f / (float)B_ROWS);
        e += pr * logf(pr + 1e-10f);
    }
    red[tid] = e;
    __syncthreads();
    for (int s = 512; s > 0; s >>= 1) {
        if (tid < s) red[tid] += red[tid + s];
        __syncthreads();
    }
    if (tid == 0) out_perp[0] = expf(-red[0]);
}

// ---------------------------------------------------------------------------
extern "C" void kernel_launch(void* const* d_in, const int* in_sizes, int n_in,
                              void* d_out, int out_size, void* d_ws, size_t ws_size,
                              hipStream_t stream)
{
    const float* x   = (const float*)d_in[0];
    const float* W1  = (const float*)d_in[1];
    const float* b1  = (const float*)d_in[2];
    const float* g1  = (const float*)d_in[3];
    const float* be1 = (const float*)d_in[4];
    const float* rm1 = (const float*)d_in[5];
    const float* rv1 = (const float*)d_in[6];
    const float* W2  = (const float*)d_in[7];
    const float* b2  = (const float*)d_in[8];
    const float* W3  = (const float*)d_in[9];
    const float* b3  = (const float*)d_in[10];
    const float* W4  = (const float*)d_in[11];
    const float* b4  = (const float*)d_in[12];
    const float* emb = (const float*)d_in[13];
    const float* Dw1 = (const float*)d_in[14];
    const float* db1 = (const float*)d_in[15];
    const float* Dw2 = (const float*)d_in[16];
    const float* db2 = (const float*)d_in[17];
    const float* Dw3 = (const float*)d_in[18];
    const float* db3 = (const float*)d_in[19];
    const float* Dw4 = (const float*)d_in[20];
    const float* db4 = (const float*)d_in[21];
    float* out = (float*)d_out;
    (void)in_sizes; (void)n_in;

    // ---- workspace carve-up (256B-aligned) ----
    char* p = (char*)d_ws;
    size_t off = 0;
    auto alloc = [&](size_t bytes) -> char* {
        char* r = p + off;
        off = (off + bytes + 255) & ~(size_t)255;
        return r;
    };
    bf16* en  = (bf16*)alloc((size_t)K_CODES * E_DIM * 2);
    bf16* W1T = (bf16*)alloc((size_t)D_IN * H_DIM * 2);
    bf16* W2T = (bf16*)alloc((size_t)H_DIM * H_DIM * 2);
    bf16* W3T = (bf16*)alloc((size_t)H_DIM * (H_DIM / 2) * 2);
    bf16* W4T = (bf16*)alloc((size_t)(H_DIM / 2) * E_DIM * 2);
    bf16* D1T = (bf16*)alloc((size_t)E_DIM * (H_DIM / 2) * 2);
    bf16* D2T = (bf16*)alloc((size_t)(H_DIM / 2) * H_DIM * 2);
    bf16* D3T = (bf16*)alloc((size_t)H_DIM * H_DIM * 2);
    bf16* D4T = (bf16*)alloc((size_t)H_DIM * D_IN * 2);
    float* s1  = (float*)alloc(H_DIM * 4);
    float* sh1 = (float*)alloc(H_DIM * 4);
    unsigned int* counts = (unsigned int*)alloc(K_CODES * 4);
    float* psum = (float*)alloc((B_ROWS / 64) * 4);
    // mini decoder-on-codebook buffers
    bf16*  XR1  = (bf16*)alloc((size_t)K_CODES * (H_DIM / 2) * 2);  // 4096x256
    bf16*  XR2  = (bf16*)alloc((size_t)K_CODES * H_DIM * 2);        // 4096x512
    bf16*  XR3  = (bf16*)alloc((size_t)K_CODES * H_DIM * 2);        // 4096x512
    float* XRcb = (float*)alloc((size_t)K_CODES * D_IN * 4);        // 4096x128 f32
    size_t fixed_bytes = off;

    // per-chunk: Xb CH*1024 + Yb CH*1024 + zb CH*128 + zn CH*128
    int CH = 128;
    for (int c = B_ROWS; c >= 128; c >>= 1) {
        if (fixed_bytes + (size_t)c * 2304 + 4096 <= ws_size) { CH = c; break; }
    }
    bf16* Xb = (bf16*)alloc((size_t)CH * H_DIM * 2);
    bf16* Yb = (bf16*)alloc((size_t)CH * H_DIM * 2);
    bf16* zb = (bf16*)alloc((size_t)CH * E_DIM * 2);
    bf16* zn = (bf16*)alloc((size_t)CH * E_DIM * 2);

    // ---- prep + transposes, one dispatch ----
    TranspArgs ta;
    ta.s[0] = W1;  ta.d[0] = W1T;
    ta.s[1] = W2;  ta.d[1] = W2T;
    ta.s[2] = W3;  ta.d[2] = W3T;
    ta.s[3] = W4;  ta.d[3] = W4T;
    ta.s[4] = Dw1; ta.d[4] = D1T;
    ta.s[5] = Dw2; ta.d[5] = D2T;
    ta.s[6] = Dw3; ta.d[6] = D3T;
    ta.s[7] = Dw4; ta.d[7] = D4T;
    prep_transp<<<1041 + 232, 256, 0, stream>>>(emb, en, counts, b1, g1, be1, rm1, rv1, s1, sh1, ta);

    dim3 blk(256);
    const GemmProb NONE = {nullptr, nullptr, nullptr, nullptr, nullptr, 0, 0, 1, 0};

    for (int c0 = 0; c0 < B_ROWS; c0 += CH) {
        const int M = CH;
        const int P = M / 128;
        const bool z = (c0 == 0);   // zip the one-time mini decoder chain
                                    // (XRcb[c]=dec(emb[c])) into chunk 0's
                                    // encoder dispatches as extra blocks

        GemmProb e1 = {x + (size_t)c0 * D_IN, W1T, s1, sh1, Xb, 512, 128, 4, P * 4};
        GemmProb m1 = {emb, D1T, nullptr, db1, XR1, 256, 64, 2, 64};
        mfma_gemm2<true , true><<<e1.nblk + (z ? m1.nblk : 0), blk, 0, stream>>>(e1, z ? m1 : NONE);

        GemmProb e2 = {Xb, W2T, nullptr, b2, Yb, 512, 512, 4, P * 4};
        GemmProb m2 = {XR1, D2T, nullptr, db2, XR2, 512, 256, 4, 128};
        mfma_gemm2<false, true><<<e2.nblk + (z ? m2.nblk : 0), blk, 0, stream>>>(e2, z ? m2 : NONE);

        GemmProb e3 = {Yb, W3T, nullptr, b3, Xb, 256, 512, 2, P * 2};
        GemmProb m3 = {XR2, D3T, nullptr, db3, XR3, 512, 512, 4, 128};
        mfma_gemm2<false, true><<<e3.nblk + (z ? m3.nblk : 0), blk, 0, stream>>>(e3, z ? m3 : NONE);

        // G4: encoder FUSE_ZN (P blocks) + zipped mini-G4 (32 blocks, once)
        mfma_gemm4<<<P + (z ? 32 : 0), blk, 0, stream>>>(Xb, W4T, b4, zb, zn, P,
                                                         XR3, D4T, db4, XRcb);

        // VQ: argmin + histogram + sumsq + x_recon scatter, one kernel
        vq_all<<<M / 64, 256, 0, stream>>>(zn, zb, en, emb, XRcb,
                                           out + 1 + (size_t)c0 * D_IN,
                                           counts, psum, c0 / 64);
    }

    finalize_k<<<1, 1024, 0, stream>>>(counts, psum, out, out + (out_size - 1));
}